// Round 1
// baseline (2751.347 us; speedup 1.0000x reference)
//
#include <hip/hip_runtime.h>
#include <hip/hip_bf16.h>
#include <math.h>

#define B_ 2
#define N_ 16384
#define M_ 2048
#define D_ 256
#define NHEAD_ 8
#define DH_ 32
#define FF_ 512
#define C_ 50
#define HID_ 128
#define HHID_ 256
#define L_ 4
#define EPS_ 1e-5f
#define TOK_ (B_*M_)   // 4096

// ---------------- fused embed + pos MLP ----------------
__global__ __launch_bounds__(128) void embed_kernel(
    const float* __restrict__ xyz,
    const float* __restrict__ ew1, const float* __restrict__ eb1,
    const float* __restrict__ ew2, const float* __restrict__ eb2,
    const float* __restrict__ pw1, const float* __restrict__ pb1,
    const float* __restrict__ pw2, const float* __restrict__ pb2,
    float* __restrict__ x) {
  int t = blockIdx.x;           // 0..4095
  int b = t / M_, m = t % M_;
  const float* p = xyz + ((size_t)b * N_ + (size_t)m * 8) * 3;
  float t0 = p[0], t1 = p[1], t2 = p[2];
  __shared__ float he[HID_], hp[HID_];
  int j = threadIdx.x;          // 128 threads
  {
    float a = fmaf(t0, ew1[j], fmaf(t1, ew1[HID_ + j], fmaf(t2, ew1[2 * HID_ + j], eb1[j])));
    he[j] = fmaxf(a, 0.f);
    float c = fmaf(t0, pw1[j], fmaf(t1, pw1[HID_ + j], fmaf(t2, pw1[2 * HID_ + j], pb1[j])));
    hp[j] = fmaxf(c, 0.f);
  }
  __syncthreads();
  for (int d = j; d < D_; d += HID_) {
    float acc = eb2[d] + pb2[d];
    for (int k = 0; k < HID_; ++k) {
      acc = fmaf(he[k], ew2[k * D_ + d], acc);
      acc = fmaf(hp[k], pw2[k * D_ + d], acc);
    }
    x[(size_t)t * D_ + d] = acc;
  }
}

// ---------------- LayerNorm (one wave per row) ----------------
__global__ __launch_bounds__(64) void ln_kernel(
    const float* __restrict__ x, const float* __restrict__ s,
    const float* __restrict__ bb, float* __restrict__ y) {
  int r = blockIdx.x;
  int t = threadIdx.x;  // 64
  const float4* xr = (const float4*)(x + (size_t)r * D_);
  float4 v = xr[t];
  float sum = v.x + v.y + v.z + v.w;
  #pragma unroll
  for (int o = 1; o < 64; o <<= 1) sum += __shfl_xor(sum, o, 64);
  float mean = sum * (1.f / D_);
  float dx = v.x - mean, dy = v.y - mean, dz = v.z - mean, dw = v.w - mean;
  float vs = dx * dx + dy * dy + dz * dz + dw * dw;
  #pragma unroll
  for (int o = 1; o < 64; o <<= 1) vs += __shfl_xor(vs, o, 64);
  float inv = 1.0f / sqrtf(vs * (1.f / D_) + EPS_);
  float4 sv = ((const float4*)s)[t];
  float4 bv = ((const float4*)bb)[t];
  float4 out;
  out.x = dx * inv * sv.x + bv.x;
  out.y = dy * inv * sv.y + bv.y;
  out.z = dz * inv * sv.z + bv.z;
  out.w = dw * inv * sv.w + bv.w;
  ((float4*)(y + (size_t)r * D_))[t] = out;
}

// ---------------- generic tiled GEMM: C = act(A@W + bias) [+ R] ----------------
// A: rows x K (rows multiple of 64), W: K x Ncols, grid (ceil(N/64), rows/64)
template <int ACT, int RES>
__global__ __launch_bounds__(256) void gemm_kernel(
    const float* __restrict__ A, const float* __restrict__ W,
    const float* __restrict__ bias, const float* __restrict__ R,
    float* __restrict__ Cc, int K, int Ncols) {
  __shared__ float As[16][68];
  __shared__ float Ws[16][68];
  int m0 = blockIdx.y * 64;
  int n0 = blockIdx.x * 64;
  int tid = threadIdx.x;  // 256
  int tx = tid & 15, ty = tid >> 4;
  float acc[4][4] = {};
  for (int kk = 0; kk < K; kk += 16) {
    for (int i = tid; i < 64 * 16; i += 256) {
      int mm = i >> 4, kq = i & 15;
      As[kq][mm] = A[(size_t)(m0 + mm) * K + kk + kq];
    }
    for (int i = tid; i < 16 * 64; i += 256) {
      int kq = i >> 6, nn = i & 63;
      int n = n0 + nn;
      Ws[kq][nn] = (n < Ncols) ? W[(size_t)(kk + kq) * Ncols + n] : 0.f;
    }
    __syncthreads();
    #pragma unroll
    for (int kq = 0; kq < 16; ++kq) {
      float a[4], w[4];
      #pragma unroll
      for (int i = 0; i < 4; ++i) a[i] = As[kq][ty * 4 + i];
      #pragma unroll
      for (int jj = 0; jj < 4; ++jj) w[jj] = Ws[kq][tx * 4 + jj];
      #pragma unroll
      for (int i = 0; i < 4; ++i)
        #pragma unroll
        for (int jj = 0; jj < 4; ++jj) acc[i][jj] = fmaf(a[i], w[jj], acc[i][jj]);
    }
    __syncthreads();
  }
  #pragma unroll
  for (int i = 0; i < 4; ++i) {
    int m = m0 + ty * 4 + i;
    #pragma unroll
    for (int jj = 0; jj < 4; ++jj) {
      int n = n0 + tx * 4 + jj;
      if (n >= Ncols) continue;
      float v = acc[i][jj] + bias[n];
      if (ACT == 1) v = fmaxf(v, 0.f);
      else if (ACT == 2) v = 0.5f * v * (1.f + erff(v * 0.70710678118654752f));
      if (RES) v += R[(size_t)m * Ncols + n];
      Cc[(size_t)m * Ncols + n] = v;
    }
  }
}

// ---------------- flash attention: one block per (b, head, 64 q-rows) ----------------
__global__ __launch_bounds__(256) void attn_kernel(
    const float* __restrict__ q, const float* __restrict__ k,
    const float* __restrict__ v, float* __restrict__ o) {
  int bid = blockIdx.x;
  int qt = bid & 31;
  int h = (bid >> 5) & 7;
  int b = bid >> 8;
  __shared__ float qs[64][33];
  __shared__ float ks[64][36];
  __shared__ float vs[64][36];
  __shared__ float ps[64][65];
  int tid = threadIdx.x;
  int r = tid >> 2, c = tid & 3;
  const size_t base = (size_t)b * M_ * D_ + (size_t)h * DH_;
  for (int i = tid; i < 64 * 32; i += 256) {
    int row = i >> 5, d = i & 31;
    qs[row][d] = q[base + (size_t)(qt * 64 + row) * D_ + d];
  }
  __syncthreads();
  float qreg[32];
  #pragma unroll
  for (int d = 0; d < 32; ++d) qreg[d] = qs[r][d];
  float m_i = -INFINITY, l_i = 0.f;
  float oacc[8];
  #pragma unroll
  for (int jj = 0; jj < 8; ++jj) oacc[jj] = 0.f;
  const float scale = 0.17677669529663687f;  // 1/sqrt(32)
  for (int kt = 0; kt < 32; ++kt) {
    __syncthreads();
    for (int i = tid; i < 64 * 32; i += 256) {
      int row = i >> 5, d = i & 31;
      ks[row][d] = k[base + (size_t)(kt * 64 + row) * D_ + d];
      vs[row][d] = v[base + (size_t)(kt * 64 + row) * D_ + d];
    }
    __syncthreads();
    float smax = -INFINITY;
    float sc[16];
    #pragma unroll
    for (int kkv = 0; kkv < 16; ++kkv) {
      int kidx = c * 16 + kkv;
      const float4* kr = (const float4*)&ks[kidx][0];
      float s = 0.f;
      #pragma unroll
      for (int d4 = 0; d4 < 8; ++d4) {
        float4 kv = kr[d4];
        s = fmaf(qreg[d4 * 4 + 0], kv.x, s);
        s = fmaf(qreg[d4 * 4 + 1], kv.y, s);
        s = fmaf(qreg[d4 * 4 + 2], kv.z, s);
        s = fmaf(qreg[d4 * 4 + 3], kv.w, s);
      }
      s *= scale;
      sc[kkv] = s;
      smax = fmaxf(smax, s);
    }
    smax = fmaxf(smax, __shfl_xor(smax, 1, 64));
    smax = fmaxf(smax, __shfl_xor(smax, 2, 64));
    float m_new = fmaxf(m_i, smax);
    float resc = expf(m_i - m_new);
    float lsum = 0.f;
    #pragma unroll
    for (int kkv = 0; kkv < 16; ++kkv) {
      float pp = expf(sc[kkv] - m_new);
      ps[r][c * 16 + kkv] = pp;
      lsum += pp;
    }
    lsum += __shfl_xor(lsum, 1, 64);
    lsum += __shfl_xor(lsum, 2, 64);
    l_i = l_i * resc + lsum;
    m_i = m_new;
    #pragma unroll
    for (int jj = 0; jj < 8; ++jj) oacc[jj] *= resc;
    for (int k2 = 0; k2 < 64; ++k2) {
      float pp = ps[r][k2];
      const float4* vr = (const float4*)&vs[k2][c * 8];
      float4 v0 = vr[0], v1 = vr[1];
      oacc[0] = fmaf(pp, v0.x, oacc[0]);
      oacc[1] = fmaf(pp, v0.y, oacc[1]);
      oacc[2] = fmaf(pp, v0.z, oacc[2]);
      oacc[3] = fmaf(pp, v0.w, oacc[3]);
      oacc[4] = fmaf(pp, v1.x, oacc[4]);
      oacc[5] = fmaf(pp, v1.y, oacc[5]);
      oacc[6] = fmaf(pp, v1.z, oacc[6]);
      oacc[7] = fmaf(pp, v1.w, oacc[7]);
    }
  }
  float invl = 1.f / l_i;
  #pragma unroll
  for (int jj = 0; jj < 8; ++jj)
    o[base + (size_t)(qt * 64 + r) * D_ + c * 8 + jj] = oacc[jj] * invl;
}

// ---------------- KNN top-3 + gather/mean ----------------
__global__ __launch_bounds__(128) void knn_kernel(
    const float* __restrict__ xyz, const float* __restrict__ lt,
    float* __restrict__ out) {
  __shared__ float tx[M_], ty[M_], tz[M_], tk2[M_];
  int b = blockIdx.x >> 7;                 // 128 blocks per batch
  int n = ((blockIdx.x & 127) << 7) + threadIdx.x;
  for (int i = threadIdx.x; i < M_; i += 128) {
    const float* tp = xyz + ((size_t)b * N_ + (size_t)i * 8) * 3;
    float a = tp[0], bb = tp[1], cc = tp[2];
    tx[i] = a; ty[i] = bb; tz[i] = cc;
    tk2[i] = a * a + bb * bb + cc * cc;
  }
  __syncthreads();
  const float* qp = xyz + ((size_t)b * N_ + n) * 3;
  float qx = qp[0], qy = qp[1], qz = qp[2];
  float q2 = qx * qx + qy * qy + qz * qz;
  float d0 = INFINITY, d1 = INFINITY, d2 = INFINITY;
  int i0 = 0, i1 = 0, i2 = 0;
  for (int m = 0; m < M_; ++m) {
    float dot = fmaf(qx, tx[m], fmaf(qy, ty[m], qz * tz[m]));
    float d = q2 + tk2[m] - 2.f * dot;
    d = fmaxf(d, 0.f);
    if (d < d2) {
      if (d < d1) {
        if (d < d0) { d2 = d1; i2 = i1; d1 = d0; i1 = i0; d0 = d; i0 = m; }
        else        { d2 = d1; i2 = i1; d1 = d;  i1 = m; }
      } else        { d2 = d;  i2 = m; }
    }
  }
  const float* l0 = lt + ((size_t)b * M_ + i0) * C_;
  const float* l1 = lt + ((size_t)b * M_ + i1) * C_;
  const float* l2 = lt + ((size_t)b * M_ + i2) * C_;
  float* op = out + ((size_t)b * N_ + n) * C_;
  for (int cc = 0; cc < C_; ++cc) op[cc] = (l0[cc] + l1[cc] + l2[cc]) / 3.0f;
}

extern "C" void kernel_launch(void* const* d_in, const int* in_sizes, int n_in,
                              void* d_out, int out_size, void* d_ws, size_t ws_size,
                              hipStream_t stream) {
  const float* xyz  = (const float*)d_in[0];
  const float* ew1  = (const float*)d_in[1];
  const float* eb1  = (const float*)d_in[2];
  const float* ew2  = (const float*)d_in[3];
  const float* eb2  = (const float*)d_in[4];
  const float* pw1  = (const float*)d_in[5];
  const float* pb1  = (const float*)d_in[6];
  const float* pw2  = (const float*)d_in[7];
  const float* pb2  = (const float*)d_in[8];
  const float* Wq   = (const float*)d_in[9];
  const float* bq   = (const float*)d_in[10];
  const float* Wk   = (const float*)d_in[11];
  const float* bk   = (const float*)d_in[12];
  const float* Wv   = (const float*)d_in[13];
  const float* bv   = (const float*)d_in[14];
  const float* Wo   = (const float*)d_in[15];
  const float* bo   = (const float*)d_in[16];
  const float* ln1s = (const float*)d_in[17];
  const float* ln1b = (const float*)d_in[18];
  const float* W1   = (const float*)d_in[19];
  const float* b1   = (const float*)d_in[20];
  const float* W2   = (const float*)d_in[21];
  const float* b2   = (const float*)d_in[22];
  const float* ln2s = (const float*)d_in[23];
  const float* ln2b = (const float*)d_in[24];
  const float* hw1  = (const float*)d_in[25];
  const float* hb1  = (const float*)d_in[26];
  const float* hw2  = (const float*)d_in[27];
  const float* hb2  = (const float*)d_in[28];
  float* out = (float*)d_out;

  float* x  = (float*)d_ws;          // 4096*256
  float* y  = x  + (size_t)TOK_ * D_;
  float* qb = y  + (size_t)TOK_ * D_;
  float* kb = qb + (size_t)TOK_ * D_;
  float* vb = kb + (size_t)TOK_ * D_;
  float* ob = vb + (size_t)TOK_ * D_;
  float* ff = ob + (size_t)TOK_ * D_;  // 4096*512
  float* lt = ff + (size_t)TOK_ * FF_; // 4096*50

  embed_kernel<<<TOK_, 128, 0, stream>>>(xyz, ew1, eb1, ew2, eb2, pw1, pb1, pw2, pb2, x);

  dim3 gD(D_ / 64, TOK_ / 64);   // (4, 64)
  dim3 gF(FF_ / 64, TOK_ / 64);  // (8, 64)
  for (int l = 0; l < L_; ++l) {
    const float* wq = Wq + (size_t)l * D_ * D_;
    const float* wk = Wk + (size_t)l * D_ * D_;
    const float* wv = Wv + (size_t)l * D_ * D_;
    const float* wo = Wo + (size_t)l * D_ * D_;
    ln_kernel<<<TOK_, 64, 0, stream>>>(x, ln1s + l * D_, ln1b + l * D_, y);
    gemm_kernel<0, 0><<<gD, 256, 0, stream>>>(y, wq, bq + l * D_, nullptr, qb, D_, D_);
    gemm_kernel<0, 0><<<gD, 256, 0, stream>>>(y, wk, bk + l * D_, nullptr, kb, D_, D_);
    gemm_kernel<0, 0><<<gD, 256, 0, stream>>>(y, wv, bv + l * D_, nullptr, vb, D_, D_);
    attn_kernel<<<512, 256, 0, stream>>>(qb, kb, vb, ob);
    gemm_kernel<0, 1><<<gD, 256, 0, stream>>>(ob, wo, bo + l * D_, x, x, D_, D_);
    ln_kernel<<<TOK_, 64, 0, stream>>>(x, ln2s + l * D_, ln2b + l * D_, y);
    gemm_kernel<2, 0><<<gF, 256, 0, stream>>>(y, W1 + (size_t)l * D_ * FF_, b1 + l * FF_, nullptr, ff, D_, FF_);
    gemm_kernel<0, 1><<<gD, 256, 0, stream>>>(ff, W2 + (size_t)l * FF_ * D_, b2 + l * D_, x, x, FF_, D_);
  }
  gemm_kernel<1, 0><<<gD, 256, 0, stream>>>(x, hw1, hb1, nullptr, y, D_, HHID_);
  gemm_kernel<0, 0><<<dim3(1, TOK_ / 64), 256, 0, stream>>>(y, hw2, hb2, nullptr, lt, HHID_, C_);
  knn_kernel<<<256, 128, 0, stream>>>(xyz, lt, out);
}

// Round 2
// 1621.074 us; speedup vs baseline: 1.6972x; 1.6972x over previous
//
#include <hip/hip_runtime.h>
#include <hip/hip_bf16.h>
#include <math.h>

#define B_ 2
#define N_ 16384
#define M_ 2048
#define D_ 256
#define NHEAD_ 8
#define DH_ 32
#define FF_ 512
#define C_ 50
#define HID_ 128
#define HHID_ 256
#define L_ 4
#define EPS_ 1e-5f
#define TOK_ (B_*M_)   // 4096

typedef short short8 __attribute__((ext_vector_type(8)));
typedef float f32x4 __attribute__((ext_vector_type(4)));

__device__ inline short f2bf(float f) {
  union { float f; unsigned u; } c; c.f = f;
  unsigned u = c.u;
  unsigned r = (u + 0x7FFFu + ((u >> 16) & 1u)) >> 16;
  return (short)r;
}
__device__ inline unsigned pack2bf(float a, float b) {
  return ((unsigned)(unsigned short)f2bf(a)) | (((unsigned)(unsigned short)f2bf(b)) << 16);
}

// ---------------- fused embed + pos MLP ----------------
__global__ __launch_bounds__(128) void embed_kernel(
    const float* __restrict__ xyz,
    const float* __restrict__ ew1, const float* __restrict__ eb1,
    const float* __restrict__ ew2, const float* __restrict__ eb2,
    const float* __restrict__ pw1, const float* __restrict__ pb1,
    const float* __restrict__ pw2, const float* __restrict__ pb2,
    float* __restrict__ x) {
  int t = blockIdx.x;           // 0..4095
  int b = t / M_, m = t % M_;
  const float* p = xyz + ((size_t)b * N_ + (size_t)m * 8) * 3;
  float t0 = p[0], t1 = p[1], t2 = p[2];
  __shared__ float he[HID_], hp[HID_];
  int j = threadIdx.x;          // 128 threads
  {
    float a = fmaf(t0, ew1[j], fmaf(t1, ew1[HID_ + j], fmaf(t2, ew1[2 * HID_ + j], eb1[j])));
    he[j] = fmaxf(a, 0.f);
    float c = fmaf(t0, pw1[j], fmaf(t1, pw1[HID_ + j], fmaf(t2, pw1[2 * HID_ + j], pb1[j])));
    hp[j] = fmaxf(c, 0.f);
  }
  __syncthreads();
  for (int d = j; d < D_; d += HID_) {
    float acc = eb2[d] + pb2[d];
    for (int k = 0; k < HID_; ++k) {
      acc = fmaf(he[k], ew2[k * D_ + d], acc);
      acc = fmaf(hp[k], pw2[k * D_ + d], acc);
    }
    x[(size_t)t * D_ + d] = acc;
  }
}

// ---------------- LayerNorm (one wave per row) ----------------
__global__ __launch_bounds__(64) void ln_kernel(
    const float* __restrict__ x, const float* __restrict__ s,
    const float* __restrict__ bb, float* __restrict__ y) {
  int r = blockIdx.x;
  int t = threadIdx.x;  // 64
  const float4* xr = (const float4*)(x + (size_t)r * D_);
  float4 v = xr[t];
  float sum = v.x + v.y + v.z + v.w;
  #pragma unroll
  for (int o = 1; o < 64; o <<= 1) sum += __shfl_xor(sum, o, 64);
  float mean = sum * (1.f / D_);
  float dx = v.x - mean, dy = v.y - mean, dz = v.z - mean, dw = v.w - mean;
  float vs = dx * dx + dy * dy + dz * dz + dw * dw;
  #pragma unroll
  for (int o = 1; o < 64; o <<= 1) vs += __shfl_xor(vs, o, 64);
  float inv = 1.0f / sqrtf(vs * (1.f / D_) + EPS_);
  float4 sv = ((const float4*)s)[t];
  float4 bv = ((const float4*)bb)[t];
  float4 out;
  out.x = dx * inv * sv.x + bv.x;
  out.y = dy * inv * sv.y + bv.y;
  out.z = dz * inv * sv.z + bv.z;
  out.w = dw * inv * sv.w + bv.w;
  ((float4*)(y + (size_t)r * D_))[t] = out;
}

// ---------------- generic tiled GEMM: C = act(A@W + bias) [+ R] ----------------
template <int ACT, int RES>
__global__ __launch_bounds__(256) void gemm_kernel(
    const float* __restrict__ A, const float* __restrict__ W,
    const float* __restrict__ bias, const float* __restrict__ R,
    float* __restrict__ Cc, int K, int Ncols) {
  __shared__ float As[16][68];
  __shared__ float Ws[16][68];
  int m0 = blockIdx.y * 64;
  int n0 = blockIdx.x * 64;
  int tid = threadIdx.x;  // 256
  int tx = tid & 15, ty = tid >> 4;
  float acc[4][4] = {};
  for (int kk = 0; kk < K; kk += 16) {
    for (int i = tid; i < 64 * 16; i += 256) {
      int mm = i >> 4, kq = i & 15;
      As[kq][mm] = A[(size_t)(m0 + mm) * K + kk + kq];
    }
    for (int i = tid; i < 16 * 64; i += 256) {
      int kq = i >> 6, nn = i & 63;
      int n = n0 + nn;
      Ws[kq][nn] = (n < Ncols) ? W[(size_t)(kk + kq) * Ncols + n] : 0.f;
    }
    __syncthreads();
    #pragma unroll
    for (int kq = 0; kq < 16; ++kq) {
      float a[4], w[4];
      #pragma unroll
      for (int i = 0; i < 4; ++i) a[i] = As[kq][ty * 4 + i];
      #pragma unroll
      for (int jj = 0; jj < 4; ++jj) w[jj] = Ws[kq][tx * 4 + jj];
      #pragma unroll
      for (int i = 0; i < 4; ++i)
        #pragma unroll
        for (int jj = 0; jj < 4; ++jj) acc[i][jj] = fmaf(a[i], w[jj], acc[i][jj]);
    }
    __syncthreads();
  }
  #pragma unroll
  for (int i = 0; i < 4; ++i) {
    int m = m0 + ty * 4 + i;
    #pragma unroll
    for (int jj = 0; jj < 4; ++jj) {
      int n = n0 + tx * 4 + jj;
      if (n >= Ncols) continue;
      float v = acc[i][jj] + bias[n];
      if (ACT == 1) v = fmaxf(v, 0.f);
      else if (ACT == 2) v = 0.5f * v * (1.f + erff(v * 0.70710678118654752f));
      if (RES) v += R[(size_t)m * Ncols + n];
      Cc[(size_t)m * Ncols + n] = v;
    }
  }
}

// ---------------- flash attention, bf16 MFMA ----------------
// grid: 512 blocks = b(2) * h(8) * qt(32); 256 threads = 4 waves * 16 q-rows
#define KSTR 40   // K_lds row stride (bf16 units), rows 16B-aligned
#define VSTR 72   // VT_lds row stride
#define PSTR 72   // P_lds row stride
__global__ __launch_bounds__(256) void attn_mfma_kernel(
    const float* __restrict__ q, const float* __restrict__ k,
    const float* __restrict__ v, float* __restrict__ o) {
  __shared__ short Ks[64][KSTR];       // 5120 B
  __shared__ short Vt[32][VSTR];       // 4608 B (V transposed)
  __shared__ short Ps[4][16][PSTR];    // 9216 B (per-wave P, bf16)
  int bid = blockIdx.x;
  int qt = bid & 31;
  int h  = (bid >> 5) & 7;
  int b  = bid >> 8;
  int tid = threadIdx.x;
  int w  = tid >> 6;
  int l  = tid & 63;
  int lq = l & 15;     // q-col within wave tile / D-col
  int lg = l >> 4;     // lane group 0..3
  const size_t base = (size_t)b * ((size_t)M_ * D_) + (size_t)h * DH_;

  // Q frag (held all kernel): row = qt*64 + w*16 + lq, k-dim d = lg*8+j
  short8 qf;
  {
    const float* qp = q + base + (size_t)(qt * 64 + w * 16 + lq) * D_ + lg * 8;
    float4 q0 = ((const float4*)qp)[0];
    float4 q1 = ((const float4*)qp)[1];
    qf[0] = f2bf(q0.x); qf[1] = f2bf(q0.y); qf[2] = f2bf(q0.z); qf[3] = f2bf(q0.w);
    qf[4] = f2bf(q1.x); qf[5] = f2bf(q1.y); qf[6] = f2bf(q1.z); qf[7] = f2bf(q1.w);
  }
  float m_i = -INFINITY, l_i = 0.f;
  f32x4 o0 = {0.f, 0.f, 0.f, 0.f};   // O^T: d = lg*4+r,      q-col = lq
  f32x4 o1 = {0.f, 0.f, 0.f, 0.f};   // O^T: d = 16 + lg*4+r, q-col = lq
  const float scale = 0.17677669529663687f;  // 1/sqrt(32)
  int srow = tid >> 2;          // staging: 4 threads/row, 8 floats each
  int scol = (tid & 3) * 8;

  for (int kt = 0; kt < M_ / 64; ++kt) {
    __syncthreads();
    {
      const float* kp = k + base + (size_t)(kt * 64 + srow) * D_ + scol;
      float4 a0 = ((const float4*)kp)[0];
      float4 a1 = ((const float4*)kp)[1];
      short8 k8;
      k8[0] = f2bf(a0.x); k8[1] = f2bf(a0.y); k8[2] = f2bf(a0.z); k8[3] = f2bf(a0.w);
      k8[4] = f2bf(a1.x); k8[5] = f2bf(a1.y); k8[6] = f2bf(a1.z); k8[7] = f2bf(a1.w);
      *(short8*)&Ks[srow][scol] = k8;
      const float* vp = v + base + (size_t)(kt * 64 + srow) * D_ + scol;
      float4 b0 = ((const float4*)vp)[0];
      float4 b1 = ((const float4*)vp)[1];
      Vt[scol + 0][srow] = f2bf(b0.x);
      Vt[scol + 1][srow] = f2bf(b0.y);
      Vt[scol + 2][srow] = f2bf(b0.z);
      Vt[scol + 3][srow] = f2bf(b0.w);
      Vt[scol + 4][srow] = f2bf(b1.x);
      Vt[scol + 5][srow] = f2bf(b1.y);
      Vt[scol + 6][srow] = f2bf(b1.z);
      Vt[scol + 7][srow] = f2bf(b1.w);
    }
    __syncthreads();
    // S^T[kv][q] = K-tile · Q^T, 4 MFMAs covering kv 0..63
    f32x4 st[4];
    #pragma unroll
    for (int t = 0; t < 4; ++t) {
      short8 kf = *(short8*)&Ks[t * 16 + lq][lg * 8];
      f32x4 z = {0.f, 0.f, 0.f, 0.f};
      st[t] = __builtin_amdgcn_mfma_f32_16x16x32_bf16(kf, qf, z, 0, 0, 0);
    }
    float smax = -INFINITY;
    #pragma unroll
    for (int t = 0; t < 4; ++t)
      #pragma unroll
      for (int r2 = 0; r2 < 4; ++r2) {
        st[t][r2] *= scale;
        smax = fmaxf(smax, st[t][r2]);
      }
    smax = fmaxf(smax, __shfl_xor(smax, 16, 64));
    smax = fmaxf(smax, __shfl_xor(smax, 32, 64));
    float m_new = fmaxf(m_i, smax);
    float fac = __expf(m_i - m_new);
    float lsum = 0.f;
    #pragma unroll
    for (int t = 0; t < 4; ++t)
      #pragma unroll
      for (int r2 = 0; r2 < 4; ++r2) {
        st[t][r2] = __expf(st[t][r2] - m_new);
        lsum += st[t][r2];
      }
    lsum += __shfl_xor(lsum, 16, 64);
    lsum += __shfl_xor(lsum, 32, 64);
    l_i = l_i * fac + lsum;
    m_i = m_new;
    #pragma unroll
    for (int r2 = 0; r2 < 4; ++r2) { o0[r2] *= fac; o1[r2] *= fac; }
    // pack P (bf16) into per-wave LDS: Ps[w][q][kv]
    {
      unsigned* pw = (unsigned*)&Ps[w][lq][0];
      #pragma unroll
      for (int t = 0; t < 4; ++t) {
        int kv = t * 16 + lg * 4;
        pw[(kv >> 1) + 0] = pack2bf(st[t][0], st[t][1]);
        pw[(kv >> 1) + 1] = pack2bf(st[t][2], st[t][3]);
      }
    }
    // O^T += V^T · P  (2 kv-chunks × 2 d-halves)
    #pragma unroll
    for (int c = 0; c < 2; ++c) {
      short8 pf = *(short8*)&Ps[w][lq][c * 32 + lg * 8];
      short8 v0 = *(short8*)&Vt[lq][c * 32 + lg * 8];
      short8 v1 = *(short8*)&Vt[16 + lq][c * 32 + lg * 8];
      o0 = __builtin_amdgcn_mfma_f32_16x16x32_bf16(v0, pf, o0, 0, 0, 0);
      o1 = __builtin_amdgcn_mfma_f32_16x16x32_bf16(v1, pf, o1, 0, 0, 0);
    }
  }
  float invl = 1.f / l_i;
  float* op = o + base + (size_t)(qt * 64 + w * 16 + lq) * D_;
  #pragma unroll
  for (int r2 = 0; r2 < 4; ++r2) {
    op[lg * 4 + r2]      = o0[r2] * invl;
    op[16 + lg * 4 + r2] = o1[r2] * invl;
  }
}

// ---------------- KNN top-3 + gather/mean ----------------
__global__ __launch_bounds__(128) void knn_kernel(
    const float* __restrict__ xyz, const float* __restrict__ lt,
    float* __restrict__ out) {
  __shared__ float tx[M_], ty[M_], tz[M_], tk2[M_];
  int b = blockIdx.x >> 7;                 // 128 blocks per batch
  int n = ((blockIdx.x & 127) << 7) + threadIdx.x;
  for (int i = threadIdx.x; i < M_; i += 128) {
    const float* tp = xyz + ((size_t)b * N_ + (size_t)i * 8) * 3;
    float a = tp[0], bb = tp[1], cc = tp[2];
    tx[i] = a; ty[i] = bb; tz[i] = cc;
    tk2[i] = a * a + bb * bb + cc * cc;
  }
  __syncthreads();
  const float* qp = xyz + ((size_t)b * N_ + n) * 3;
  float qx = qp[0], qy = qp[1], qz = qp[2];
  float q2 = qx * qx + qy * qy + qz * qz;
  float d0 = INFINITY, d1 = INFINITY, d2 = INFINITY;
  int i0 = 0, i1 = 0, i2 = 0;
  for (int m = 0; m < M_; ++m) {
    float dot = fmaf(qx, tx[m], fmaf(qy, ty[m], qz * tz[m]));
    float d = q2 + tk2[m] - 2.f * dot;
    d = fmaxf(d, 0.f);
    if (d < d2) {
      if (d < d1) {
        if (d < d0) { d2 = d1; i2 = i1; d1 = d0; i1 = i0; d0 = d; i0 = m; }
        else        { d2 = d1; i2 = i1; d1 = d;  i1 = m; }
      } else        { d2 = d;  i2 = m; }
    }
  }
  const float* l0 = lt + ((size_t)b * M_ + i0) * C_;
  const float* l1 = lt + ((size_t)b * M_ + i1) * C_;
  const float* l2 = lt + ((size_t)b * M_ + i2) * C_;
  float* op = out + ((size_t)b * N_ + n) * C_;
  for (int cc = 0; cc < C_; ++cc) op[cc] = (l0[cc] + l1[cc] + l2[cc]) / 3.0f;
}

extern "C" void kernel_launch(void* const* d_in, const int* in_sizes, int n_in,
                              void* d_out, int out_size, void* d_ws, size_t ws_size,
                              hipStream_t stream) {
  const float* xyz  = (const float*)d_in[0];
  const float* ew1  = (const float*)d_in[1];
  const float* eb1  = (const float*)d_in[2];
  const float* ew2  = (const float*)d_in[3];
  const float* eb2  = (const float*)d_in[4];
  const float* pw1  = (const float*)d_in[5];
  const float* pb1  = (const float*)d_in[6];
  const float* pw2  = (const float*)d_in[7];
  const float* pb2  = (const float*)d_in[8];
  const float* Wq   = (const float*)d_in[9];
  const float* bq   = (const float*)d_in[10];
  const float* Wk   = (const float*)d_in[11];
  const float* bk   = (const float*)d_in[12];
  const float* Wv   = (const float*)d_in[13];
  const float* bv   = (const float*)d_in[14];
  const float* Wo   = (const float*)d_in[15];
  const float* bo   = (const float*)d_in[16];
  const float* ln1s = (const float*)d_in[17];
  const float* ln1b = (const float*)d_in[18];
  const float* W1   = (const float*)d_in[19];
  const float* b1   = (const float*)d_in[20];
  const float* W2   = (const float*)d_in[21];
  const float* b2   = (const float*)d_in[22];
  const float* ln2s = (const float*)d_in[23];
  const float* ln2b = (const float*)d_in[24];
  const float* hw1  = (const float*)d_in[25];
  const float* hb1  = (const float*)d_in[26];
  const float* hw2  = (const float*)d_in[27];
  const float* hb2  = (const float*)d_in[28];
  float* out = (float*)d_out;

  float* x  = (float*)d_ws;          // 4096*256
  float* y  = x  + (size_t)TOK_ * D_;
  float* qb = y  + (size_t)TOK_ * D_;
  float* kb = qb + (size_t)TOK_ * D_;
  float* vb = kb + (size_t)TOK_ * D_;
  float* ob = vb + (size_t)TOK_ * D_;
  float* ff = ob + (size_t)TOK_ * D_;  // 4096*512
  float* lt = ff + (size_t)TOK_ * FF_; // 4096*50

  embed_kernel<<<TOK_, 128, 0, stream>>>(xyz, ew1, eb1, ew2, eb2, pw1, pb1, pw2, pb2, x);

  dim3 gD(D_ / 64, TOK_ / 64);   // (4, 64)
  dim3 gF(FF_ / 64, TOK_ / 64);  // (8, 64)
  for (int l = 0; l < L_; ++l) {
    const float* wq = Wq + (size_t)l * D_ * D_;
    const float* wk = Wk + (size_t)l * D_ * D_;
    const float* wv = Wv + (size_t)l * D_ * D_;
    const float* wo = Wo + (size_t)l * D_ * D_;
    ln_kernel<<<TOK_, 64, 0, stream>>>(x, ln1s + l * D_, ln1b + l * D_, y);
    gemm_kernel<0, 0><<<gD, 256, 0, stream>>>(y, wq, bq + l * D_, nullptr, qb, D_, D_);
    gemm_kernel<0, 0><<<gD, 256, 0, stream>>>(y, wk, bk + l * D_, nullptr, kb, D_, D_);
    gemm_kernel<0, 0><<<gD, 256, 0, stream>>>(y, wv, bv + l * D_, nullptr, vb, D_, D_);
    attn_mfma_kernel<<<512, 256, 0, stream>>>(qb, kb, vb, ob);
    gemm_kernel<0, 1><<<gD, 256, 0, stream>>>(ob, wo, bo + l * D_, x, x, D_, D_);
    ln_kernel<<<TOK_, 64, 0, stream>>>(x, ln2s + l * D_, ln2b + l * D_, y);
    gemm_kernel<2, 0><<<gF, 256, 0, stream>>>(y, W1 + (size_t)l * D_ * FF_, b1 + l * FF_, nullptr, ff, D_, FF_);
    gemm_kernel<0, 1><<<gD, 256, 0, stream>>>(ff, W2 + (size_t)l * FF_ * D_, b2 + l * D_, x, x, FF_, D_);
  }
  gemm_kernel<1, 0><<<gD, 256, 0, stream>>>(x, hw1, hb1, nullptr, y, D_, HHID_);
  gemm_kernel<0, 0><<<dim3(1, TOK_ / 64), 256, 0, stream>>>(y, hw2, hb2, nullptr, lt, HHID_, C_);
  knn_kernel<<<256, 128, 0, stream>>>(xyz, lt, out);
}

// Round 3
// 661.753 us; speedup vs baseline: 4.1577x; 2.4497x over previous
//
#include <hip/hip_runtime.h>
#include <hip/hip_bf16.h>
#include <math.h>

#define B_ 2
#define N_ 16384
#define M_ 2048
#define D_ 256
#define NHEAD_ 8
#define DH_ 32
#define FF_ 512
#define C_ 50
#define HID_ 128
#define HHID_ 256
#define L_ 4
#define EPS_ 1e-5f
#define TOK_ (B_*M_)   // 4096

typedef short short8 __attribute__((ext_vector_type(8)));
typedef float f32x4 __attribute__((ext_vector_type(4)));

__device__ __forceinline__ short f2bf(float f) {
  union { float f; unsigned u; } c; c.f = f;
  unsigned u = c.u;
  unsigned r = (u + 0x7FFFu + ((u >> 16) & 1u)) >> 16;
  return (short)r;
}
__device__ __forceinline__ unsigned pack2bf(float a, float b) {
  return ((unsigned)(unsigned short)f2bf(a)) | (((unsigned)(unsigned short)f2bf(b)) << 16);
}

// ---------------- fused embed + pos MLP ----------------
__global__ __launch_bounds__(128) void embed_kernel(
    const float* __restrict__ xyz,
    const float* __restrict__ ew1, const float* __restrict__ eb1,
    const float* __restrict__ ew2, const float* __restrict__ eb2,
    const float* __restrict__ pw1, const float* __restrict__ pb1,
    const float* __restrict__ pw2, const float* __restrict__ pb2,
    float* __restrict__ x) {
  int t = blockIdx.x;           // 0..4095
  int b = t / M_, m = t % M_;
  const float* p = xyz + ((size_t)b * N_ + (size_t)m * 8) * 3;
  float t0 = p[0], t1 = p[1], t2 = p[2];
  __shared__ float he[HID_], hp[HID_];
  int j = threadIdx.x;          // 128 threads
  {
    float a = fmaf(t0, ew1[j], fmaf(t1, ew1[HID_ + j], fmaf(t2, ew1[2 * HID_ + j], eb1[j])));
    he[j] = fmaxf(a, 0.f);
    float c = fmaf(t0, pw1[j], fmaf(t1, pw1[HID_ + j], fmaf(t2, pw1[2 * HID_ + j], pb1[j])));
    hp[j] = fmaxf(c, 0.f);
  }
  __syncthreads();
  for (int d = j; d < D_; d += HID_) {
    float acc = eb2[d] + pb2[d];
    for (int k = 0; k < HID_; ++k) {
      acc = fmaf(he[k], ew2[k * D_ + d], acc);
      acc = fmaf(hp[k], pw2[k * D_ + d], acc);
    }
    x[(size_t)t * D_ + d] = acc;
  }
}

// ---------------- LayerNorm (one wave per row) ----------------
__global__ __launch_bounds__(64) void ln_kernel(
    const float* __restrict__ x, const float* __restrict__ s,
    const float* __restrict__ bb, float* __restrict__ y) {
  int r = blockIdx.x;
  int t = threadIdx.x;  // 64
  const float4* xr = (const float4*)(x + (size_t)r * D_);
  float4 v = xr[t];
  float sum = v.x + v.y + v.z + v.w;
  #pragma unroll
  for (int o = 1; o < 64; o <<= 1) sum += __shfl_xor(sum, o, 64);
  float mean = sum * (1.f / D_);
  float dx = v.x - mean, dy = v.y - mean, dz = v.z - mean, dw = v.w - mean;
  float vs = dx * dx + dy * dy + dz * dz + dw * dw;
  #pragma unroll
  for (int o = 1; o < 64; o <<= 1) vs += __shfl_xor(vs, o, 64);
  float inv = 1.0f / sqrtf(vs * (1.f / D_) + EPS_);
  float4 sv = ((const float4*)s)[t];
  float4 bv = ((const float4*)bb)[t];
  float4 out;
  out.x = dx * inv * sv.x + bv.x;
  out.y = dy * inv * sv.y + bv.y;
  out.z = dz * inv * sv.z + bv.z;
  out.w = dw * inv * sv.w + bv.w;
  ((float4*)(y + (size_t)r * D_))[t] = out;
}

// ---------------- fp32 tiled GEMM (kept for head2, N=50) ----------------
template <int ACT, int RES>
__global__ __launch_bounds__(256) void gemm_kernel(
    const float* __restrict__ A, const float* __restrict__ W,
    const float* __restrict__ bias, const float* __restrict__ R,
    float* __restrict__ Cc, int K, int Ncols) {
  __shared__ float As[16][68];
  __shared__ float Ws[16][68];
  int m0 = blockIdx.y * 64;
  int n0 = blockIdx.x * 64;
  int tid = threadIdx.x;  // 256
  int tx = tid & 15, ty = tid >> 4;
  float acc[4][4] = {};
  for (int kk = 0; kk < K; kk += 16) {
    for (int i = tid; i < 64 * 16; i += 256) {
      int mm = i >> 4, kq = i & 15;
      As[kq][mm] = A[(size_t)(m0 + mm) * K + kk + kq];
    }
    for (int i = tid; i < 16 * 64; i += 256) {
      int kq = i >> 6, nn = i & 63;
      int n = n0 + nn;
      Ws[kq][nn] = (n < Ncols) ? W[(size_t)(kk + kq) * Ncols + n] : 0.f;
    }
    __syncthreads();
    #pragma unroll
    for (int kq = 0; kq < 16; ++kq) {
      float a[4], w[4];
      #pragma unroll
      for (int i = 0; i < 4; ++i) a[i] = As[kq][ty * 4 + i];
      #pragma unroll
      for (int jj = 0; jj < 4; ++jj) w[jj] = Ws[kq][tx * 4 + jj];
      #pragma unroll
      for (int i = 0; i < 4; ++i)
        #pragma unroll
        for (int jj = 0; jj < 4; ++jj) acc[i][jj] = fmaf(a[i], w[jj], acc[i][jj]);
    }
    __syncthreads();
  }
  #pragma unroll
  for (int i = 0; i < 4; ++i) {
    int m = m0 + ty * 4 + i;
    #pragma unroll
    for (int jj = 0; jj < 4; ++jj) {
      int n = n0 + tx * 4 + jj;
      if (n >= Ncols) continue;
      float v = acc[i][jj] + bias[n];
      if (ACT == 1) v = fmaxf(v, 0.f);
      else if (ACT == 2) v = 0.5f * v * (1.f + erff(v * 0.70710678118654752f));
      if (RES) v += R[(size_t)m * Ncols + n];
      Cc[(size_t)m * Ncols + n] = v;
    }
  }
}

// ---------------- bf16 MFMA GEMM: BM=32, BN=64, BK=32, 4 waves (16x32 each) ----------------
template <int ACT, int RES>
__device__ __forceinline__ void gemm_body(
    const float* __restrict__ A, const float* __restrict__ W,
    const float* __restrict__ bias, const float* __restrict__ R,
    float* __restrict__ Cc, int K, int Ncols, int m0, int n0) {
  __shared__ short As[32][40];
  __shared__ short Bs[64][40];
  int tid = threadIdx.x;
  int w = tid >> 6, l = tid & 63;
  int lq = l & 15, lg = l >> 4;
  int wr = (w & 1) * 16, wc = (w >> 1) * 32;
  int ar = tid >> 3, ak = (tid & 7) * 4;
  int wn = tid & 63, wk = (tid >> 6) * 8;
  f32x4 acc0 = {0.f, 0.f, 0.f, 0.f};
  f32x4 acc1 = {0.f, 0.f, 0.f, 0.f};
  for (int kk = 0; kk < K; kk += 32) {
    __syncthreads();
    {
      float4 a4 = *(const float4*)(A + (size_t)(m0 + ar) * K + kk + ak);
      uint2 au;
      au.x = pack2bf(a4.x, a4.y);
      au.y = pack2bf(a4.z, a4.w);
      *(uint2*)&As[ar][ak] = au;
      const float* wp = W + (size_t)(kk + wk) * Ncols + n0 + wn;
      float w0 = wp[0];
      float w1 = wp[(size_t)Ncols];
      float w2 = wp[2 * (size_t)Ncols];
      float w3 = wp[3 * (size_t)Ncols];
      float w4 = wp[4 * (size_t)Ncols];
      float w5 = wp[5 * (size_t)Ncols];
      float w6 = wp[6 * (size_t)Ncols];
      float w7 = wp[7 * (size_t)Ncols];
      uint4 wu;
      wu.x = pack2bf(w0, w1); wu.y = pack2bf(w2, w3);
      wu.z = pack2bf(w4, w5); wu.w = pack2bf(w6, w7);
      *(uint4*)&Bs[wn][wk] = wu;
    }
    __syncthreads();
    short8 af = *(short8*)&As[wr + lq][lg * 8];
    short8 b0 = *(short8*)&Bs[wc + lq][lg * 8];
    short8 b1 = *(short8*)&Bs[wc + 16 + lq][lg * 8];
    acc0 = __builtin_amdgcn_mfma_f32_16x16x32_bf16(af, b0, acc0, 0, 0, 0);
    acc1 = __builtin_amdgcn_mfma_f32_16x16x32_bf16(af, b1, acc1, 0, 0, 0);
  }
  int row = m0 + wr + lg * 4;
  #pragma unroll
  for (int r = 0; r < 4; ++r) {
    #pragma unroll
    for (int fj = 0; fj < 2; ++fj) {
      int col = n0 + wc + fj * 16 + lq;
      float v = (fj ? acc1[r] : acc0[r]) + bias[col];
      if (ACT == 1) v = fmaxf(v, 0.f);
      else if (ACT == 2) v = 0.5f * v * (1.f + erff(v * 0.70710678118654752f));
      if (RES) v += R[(size_t)(row + r) * Ncols + col];
      Cc[(size_t)(row + r) * Ncols + col] = v;
    }
  }
}

template <int ACT, int RES>
__global__ __launch_bounds__(256) void gemm_mfma(
    const float* __restrict__ A, const float* __restrict__ W,
    const float* __restrict__ bias, const float* __restrict__ R,
    float* __restrict__ Cc, int K, int Ncols) {
  gemm_body<ACT, RES>(A, W, bias, R, Cc, K, Ncols, blockIdx.y * 32, blockIdx.x * 64);
}

__global__ __launch_bounds__(256) void qkv_mfma(
    const float* __restrict__ A,
    const float* __restrict__ Wq, const float* __restrict__ Wk, const float* __restrict__ Wv,
    const float* __restrict__ bq, const float* __restrict__ bk, const float* __restrict__ bv,
    float* __restrict__ qb, float* __restrict__ kb, float* __restrict__ vb) {
  int sel = blockIdx.x >> 2;
  int n0 = (blockIdx.x & 3) << 6;
  const float* W = sel == 0 ? Wq : (sel == 1 ? Wk : Wv);
  const float* bb = sel == 0 ? bq : (sel == 1 ? bk : bv);
  float* Cc = sel == 0 ? qb : (sel == 1 ? kb : vb);
  gemm_body<0, 0>(A, W, bb, nullptr, Cc, D_, D_, blockIdx.y * 32, n0);
}

// ---------------- flash attention, bf16 MFMA ----------------
#define KSTR 40
#define VSTR 72
#define PSTR 72
__global__ __launch_bounds__(256) void attn_mfma_kernel(
    const float* __restrict__ q, const float* __restrict__ k,
    const float* __restrict__ v, float* __restrict__ o) {
  __shared__ short Ks[64][KSTR];
  __shared__ short Vt[32][VSTR];
  __shared__ short Ps[4][16][PSTR];
  int bid = blockIdx.x;
  int qt = bid & 31;
  int h  = (bid >> 5) & 7;
  int b  = bid >> 8;
  int tid = threadIdx.x;
  int w  = tid >> 6;
  int l  = tid & 63;
  int lq = l & 15;
  int lg = l >> 4;
  const size_t base = (size_t)b * ((size_t)M_ * D_) + (size_t)h * DH_;

  short8 qf;
  {
    const float* qp = q + base + (size_t)(qt * 64 + w * 16 + lq) * D_ + lg * 8;
    float4 q0 = ((const float4*)qp)[0];
    float4 q1 = ((const float4*)qp)[1];
    qf[0] = f2bf(q0.x); qf[1] = f2bf(q0.y); qf[2] = f2bf(q0.z); qf[3] = f2bf(q0.w);
    qf[4] = f2bf(q1.x); qf[5] = f2bf(q1.y); qf[6] = f2bf(q1.z); qf[7] = f2bf(q1.w);
  }
  float m_i = -INFINITY, l_i = 0.f;
  f32x4 o0 = {0.f, 0.f, 0.f, 0.f};
  f32x4 o1 = {0.f, 0.f, 0.f, 0.f};
  const float scale = 0.17677669529663687f;
  int srow = tid >> 2;
  int scol = (tid & 3) * 8;

  for (int kt = 0; kt < M_ / 64; ++kt) {
    __syncthreads();
    {
      const float* kp = k + base + (size_t)(kt * 64 + srow) * D_ + scol;
      float4 a0 = ((const float4*)kp)[0];
      float4 a1 = ((const float4*)kp)[1];
      short8 k8;
      k8[0] = f2bf(a0.x); k8[1] = f2bf(a0.y); k8[2] = f2bf(a0.z); k8[3] = f2bf(a0.w);
      k8[4] = f2bf(a1.x); k8[5] = f2bf(a1.y); k8[6] = f2bf(a1.z); k8[7] = f2bf(a1.w);
      *(short8*)&Ks[srow][scol] = k8;
      const float* vp = v + base + (size_t)(kt * 64 + srow) * D_ + scol;
      float4 b0 = ((const float4*)vp)[0];
      float4 b1 = ((const float4*)vp)[1];
      Vt[scol + 0][srow] = f2bf(b0.x);
      Vt[scol + 1][srow] = f2bf(b0.y);
      Vt[scol + 2][srow] = f2bf(b0.z);
      Vt[scol + 3][srow] = f2bf(b0.w);
      Vt[scol + 4][srow] = f2bf(b1.x);
      Vt[scol + 5][srow] = f2bf(b1.y);
      Vt[scol + 6][srow] = f2bf(b1.z);
      Vt[scol + 7][srow] = f2bf(b1.w);
    }
    __syncthreads();
    f32x4 st[4];
    #pragma unroll
    for (int t = 0; t < 4; ++t) {
      short8 kf = *(short8*)&Ks[t * 16 + lq][lg * 8];
      f32x4 z = {0.f, 0.f, 0.f, 0.f};
      st[t] = __builtin_amdgcn_mfma_f32_16x16x32_bf16(kf, qf, z, 0, 0, 0);
    }
    float smax = -INFINITY;
    #pragma unroll
    for (int t = 0; t < 4; ++t)
      #pragma unroll
      for (int r2 = 0; r2 < 4; ++r2) {
        st[t][r2] *= scale;
        smax = fmaxf(smax, st[t][r2]);
      }
    smax = fmaxf(smax, __shfl_xor(smax, 16, 64));
    smax = fmaxf(smax, __shfl_xor(smax, 32, 64));
    float m_new = fmaxf(m_i, smax);
    float fac = __expf(m_i - m_new);
    float lsum = 0.f;
    #pragma unroll
    for (int t = 0; t < 4; ++t)
      #pragma unroll
      for (int r2 = 0; r2 < 4; ++r2) {
        st[t][r2] = __expf(st[t][r2] - m_new);
        lsum += st[t][r2];
      }
    lsum += __shfl_xor(lsum, 16, 64);
    lsum += __shfl_xor(lsum, 32, 64);
    l_i = l_i * fac + lsum;
    m_i = m_new;
    #pragma unroll
    for (int r2 = 0; r2 < 4; ++r2) { o0[r2] *= fac; o1[r2] *= fac; }
    {
      unsigned* pw = (unsigned*)&Ps[w][lq][0];
      #pragma unroll
      for (int t = 0; t < 4; ++t) {
        int kv = t * 16 + lg * 4;
        pw[(kv >> 1) + 0] = pack2bf(st[t][0], st[t][1]);
        pw[(kv >> 1) + 1] = pack2bf(st[t][2], st[t][3]);
      }
    }
    #pragma unroll
    for (int c = 0; c < 2; ++c) {
      short8 pf = *(short8*)&Ps[w][lq][c * 32 + lg * 8];
      short8 v0 = *(short8*)&Vt[lq][c * 32 + lg * 8];
      short8 v1 = *(short8*)&Vt[16 + lq][c * 32 + lg * 8];
      o0 = __builtin_amdgcn_mfma_f32_16x16x32_bf16(v0, pf, o0, 0, 0, 0);
      o1 = __builtin_amdgcn_mfma_f32_16x16x32_bf16(v1, pf, o1, 0, 0, 0);
    }
  }
  float invl = 1.f / l_i;
  float* op = o + base + (size_t)(qt * 64 + w * 16 + lq) * D_;
  #pragma unroll
  for (int r2 = 0; r2 < 4; ++r2) {
    op[lg * 4 + r2]      = o0[r2] * invl;
    op[16 + lg * 4 + r2] = o1[r2] * invl;
  }
}

// ---------------- KNN top-3 + gather/mean: 8 lanes per query ----------------
__global__ __launch_bounds__(256) void knn_kernel(
    const float* __restrict__ xyz, const float* __restrict__ lt,
    float* __restrict__ out) {
  __shared__ float4 tok[M_];   // 32 KB: x,y,z,|t|^2
  int b = blockIdx.x >> 9;                  // 512 blocks per batch
  int q0 = (blockIdx.x & 511) << 5;         // 32 queries per block
  int tid = threadIdx.x;
  for (int i = tid; i < M_; i += 256) {
    const float* tp = xyz + ((size_t)b * N_ + (size_t)i * 8) * 3;
    float a = tp[0], bb = tp[1], cc = tp[2];
    tok[i] = make_float4(a, bb, cc, a * a + bb * bb + cc * cc);
  }
  __syncthreads();
  int qi = tid >> 3, sl = tid & 7;
  int n = q0 + qi;
  const float* qp = xyz + ((size_t)b * N_ + n) * 3;
  float qx = qp[0], qy = qp[1], qz = qp[2];
  float q2 = qx * qx + qy * qy + qz * qz;
  float d0 = INFINITY, d1 = INFINITY, d2 = INFINITY;
  int i0 = 0, i1 = 0, i2 = 0;
  auto ins = [&](float d, int i) {
    if (d < d2 || (d == d2 && i < i2)) {
      if (d < d0 || (d == d0 && i < i0)) { d2 = d1; i2 = i1; d1 = d0; i1 = i0; d0 = d; i0 = i; }
      else if (d < d1 || (d == d1 && i < i1)) { d2 = d1; i2 = i1; d1 = d; i1 = i; }
      else { d2 = d; i2 = i; }
    }
  };
  int mbase = sl << 8;
  for (int j = 0; j < 256; ++j) {
    int m = mbase + ((j + sl) & 255);     // bank-staggered scan
    float4 t = tok[m];
    float dot = fmaf(qx, t.x, fmaf(qy, t.y, qz * t.z));
    float d = fmaxf(q2 + t.w - 2.f * dot, 0.f);
    ins(d, m);
  }
  #pragma unroll
  for (int off = 1; off < 8; off <<= 1) {
    float pd0 = __shfl_xor(d0, off, 64); int pi0 = __shfl_xor(i0, off, 64);
    float pd1 = __shfl_xor(d1, off, 64); int pi1 = __shfl_xor(i1, off, 64);
    float pd2 = __shfl_xor(d2, off, 64); int pi2 = __shfl_xor(i2, off, 64);
    ins(pd0, pi0); ins(pd1, pi1); ins(pd2, pi2);
  }
  const float* l0 = lt + ((size_t)b * M_ + i0) * C_;
  const float* l1 = lt + ((size_t)b * M_ + i1) * C_;
  const float* l2 = lt + ((size_t)b * M_ + i2) * C_;
  float* op = out + ((size_t)b * N_ + n) * C_;
  for (int cc = sl; cc < C_; cc += 8)
    op[cc] = (l0[cc] + l1[cc] + l2[cc]) * (1.f / 3.f);
}

extern "C" void kernel_launch(void* const* d_in, const int* in_sizes, int n_in,
                              void* d_out, int out_size, void* d_ws, size_t ws_size,
                              hipStream_t stream) {
  const float* xyz  = (const float*)d_in[0];
  const float* ew1  = (const float*)d_in[1];
  const float* eb1  = (const float*)d_in[2];
  const float* ew2  = (const float*)d_in[3];
  const float* eb2  = (const float*)d_in[4];
  const float* pw1  = (const float*)d_in[5];
  const float* pb1  = (const float*)d_in[6];
  const float* pw2  = (const float*)d_in[7];
  const float* pb2  = (const float*)d_in[8];
  const float* Wq   = (const float*)d_in[9];
  const float* bq   = (const float*)d_in[10];
  const float* Wk   = (const float*)d_in[11];
  const float* bk   = (const float*)d_in[12];
  const float* Wv   = (const float*)d_in[13];
  const float* bv   = (const float*)d_in[14];
  const float* Wo   = (const float*)d_in[15];
  const float* bo   = (const float*)d_in[16];
  const float* ln1s = (const float*)d_in[17];
  const float* ln1b = (const float*)d_in[18];
  const float* W1   = (const float*)d_in[19];
  const float* b1   = (const float*)d_in[20];
  const float* W2   = (const float*)d_in[21];
  const float* b2   = (const float*)d_in[22];
  const float* ln2s = (const float*)d_in[23];
  const float* ln2b = (const float*)d_in[24];
  const float* hw1  = (const float*)d_in[25];
  const float* hb1  = (const float*)d_in[26];
  const float* hw2  = (const float*)d_in[27];
  const float* hb2  = (const float*)d_in[28];
  float* out = (float*)d_out;

  float* x  = (float*)d_ws;          // 4096*256
  float* y  = x  + (size_t)TOK_ * D_;
  float* qb = y  + (size_t)TOK_ * D_;
  float* kb = qb + (size_t)TOK_ * D_;
  float* vb = kb + (size_t)TOK_ * D_;
  float* ob = vb + (size_t)TOK_ * D_;
  float* ff = ob + (size_t)TOK_ * D_;  // 4096*512
  float* lt = ff + (size_t)TOK_ * FF_; // 4096*50

  embed_kernel<<<TOK_, 128, 0, stream>>>(xyz, ew1, eb1, ew2, eb2, pw1, pb1, pw2, pb2, x);

  dim3 gQKV(12, TOK_ / 32);  // (12, 128)
  dim3 gD(D_ / 64, TOK_ / 32);    // (4, 128)
  dim3 gF(FF_ / 64, TOK_ / 32);   // (8, 128)
  for (int l = 0; l < L_; ++l) {
    const float* wq = Wq + (size_t)l * D_ * D_;
    const float* wk = Wk + (size_t)l * D_ * D_;
    const float* wv = Wv + (size_t)l * D_ * D_;
    const float* wo = Wo + (size_t)l * D_ * D_;
    ln_kernel<<<TOK_, 64, 0, stream>>>(x, ln1s + l * D_, ln1b + l * D_, y);
    qkv_mfma<<<gQKV, 256, 0, stream>>>(y, wq, wk, wv, bq + l * D_, bk + l * D_, bv + l * D_, qb, kb, vb);
    attn_mfma_kernel<<<512, 256, 0, stream>>>(qb, kb, vb, ob);
    gemm_mfma<0, 1><<<gD, 256, 0, stream>>>(ob, wo, bo + l * D_, x, x, D_, D_);
    ln_kernel<<<TOK_, 64, 0, stream>>>(x, ln2s + l * D_, ln2b + l * D_, y);
    gemm_mfma<2, 0><<<gF, 256, 0, stream>>>(y, W1 + (size_t)l * D_ * FF_, b1 + l * FF_, nullptr, ff, D_, FF_);
    gemm_mfma<0, 1><<<gD, 256, 0, stream>>>(ff, W2 + (size_t)l * FF_ * D_, b2 + l * D_, x, x, FF_, D_);
  }
  gemm_mfma<1, 0><<<dim3(HHID_ / 64, TOK_ / 32), 256, 0, stream>>>(x, hw1, hb1, nullptr, y, D_, HHID_);
  gemm_kernel<0, 0><<<dim3(1, TOK_ / 64), 256, 0, stream>>>(y, hw2, hb2, nullptr, lt, HHID_, C_);
  knn_kernel<<<1024, 256, 0, stream>>>(xyz, lt, out);
}

// Round 4
// 535.835 us; speedup vs baseline: 5.1347x; 1.2350x over previous
//
#include <hip/hip_runtime.h>
#include <hip/hip_bf16.h>
#include <math.h>

#define B_ 2
#define N_ 16384
#define M_ 2048
#define D_ 256
#define NHEAD_ 8
#define DH_ 32
#define FF_ 512
#define C_ 50
#define HID_ 128
#define HHID_ 256
#define L_ 4
#define EPS_ 1e-5f
#define TOK_ (B_*M_)   // 4096

typedef short short8 __attribute__((ext_vector_type(8)));
typedef float f32x4 __attribute__((ext_vector_type(4)));

__device__ __forceinline__ short f2bf(float f) {
  union { float f; unsigned u; } c; c.f = f;
  unsigned u = c.u;
  unsigned r = (u + 0x7FFFu + ((u >> 16) & 1u)) >> 16;
  return (short)r;
}
__device__ __forceinline__ unsigned pack2bf(float a, float b) {
  return ((unsigned)(unsigned short)f2bf(a)) | (((unsigned)(unsigned short)f2bf(b)) << 16);
}

// ---------------- fused embed + pos MLP ----------------
__global__ __launch_bounds__(128) void embed_kernel(
    const float* __restrict__ xyz,
    const float* __restrict__ ew1, const float* __restrict__ eb1,
    const float* __restrict__ ew2, const float* __restrict__ eb2,
    const float* __restrict__ pw1, const float* __restrict__ pb1,
    const float* __restrict__ pw2, const float* __restrict__ pb2,
    float* __restrict__ x) {
  int t = blockIdx.x;           // 0..4095
  int b = t / M_, m = t % M_;
  const float* p = xyz + ((size_t)b * N_ + (size_t)m * 8) * 3;
  float t0 = p[0], t1 = p[1], t2 = p[2];
  __shared__ float he[HID_], hp[HID_];
  int j = threadIdx.x;          // 128 threads
  {
    float a = fmaf(t0, ew1[j], fmaf(t1, ew1[HID_ + j], fmaf(t2, ew1[2 * HID_ + j], eb1[j])));
    he[j] = fmaxf(a, 0.f);
    float c = fmaf(t0, pw1[j], fmaf(t1, pw1[HID_ + j], fmaf(t2, pw1[2 * HID_ + j], pb1[j])));
    hp[j] = fmaxf(c, 0.f);
  }
  __syncthreads();
  for (int d = j; d < D_; d += HID_) {
    float acc = eb2[d] + pb2[d];
    for (int k = 0; k < HID_; ++k) {
      acc = fmaf(he[k], ew2[k * D_ + d], acc);
      acc = fmaf(hp[k], pw2[k * D_ + d], acc);
    }
    x[(size_t)t * D_ + d] = acc;
  }
}

// ---------------- LayerNorm (one wave per row) ----------------
__global__ __launch_bounds__(64) void ln_kernel(
    const float* __restrict__ x, const float* __restrict__ s,
    const float* __restrict__ bb, float* __restrict__ y) {
  int r = blockIdx.x;
  int t = threadIdx.x;  // 64
  const float4* xr = (const float4*)(x + (size_t)r * D_);
  float4 v = xr[t];
  float sum = v.x + v.y + v.z + v.w;
  #pragma unroll
  for (int o = 1; o < 64; o <<= 1) sum += __shfl_xor(sum, o, 64);
  float mean = sum * (1.f / D_);
  float dx = v.x - mean, dy = v.y - mean, dz = v.z - mean, dw = v.w - mean;
  float vs = dx * dx + dy * dy + dz * dz + dw * dw;
  #pragma unroll
  for (int o = 1; o < 64; o <<= 1) vs += __shfl_xor(vs, o, 64);
  float inv = 1.0f / sqrtf(vs * (1.f / D_) + EPS_);
  float4 sv = ((const float4*)s)[t];
  float4 bv = ((const float4*)bb)[t];
  float4 out;
  out.x = dx * inv * sv.x + bv.x;
  out.y = dy * inv * sv.y + bv.y;
  out.z = dz * inv * sv.z + bv.z;
  out.w = dw * inv * sv.w + bv.w;
  ((float4*)(y + (size_t)r * D_))[t] = out;
}

// ---------------- fp32 tiled GEMM (kept for head2, N=50) ----------------
template <int ACT, int RES>
__global__ __launch_bounds__(256) void gemm_kernel(
    const float* __restrict__ A, const float* __restrict__ W,
    const float* __restrict__ bias, const float* __restrict__ R,
    float* __restrict__ Cc, int K, int Ncols) {
  __shared__ float As[16][68];
  __shared__ float Ws[16][68];
  int m0 = blockIdx.y * 64;
  int n0 = blockIdx.x * 64;
  int tid = threadIdx.x;  // 256
  int tx = tid & 15, ty = tid >> 4;
  float acc[4][4] = {};
  for (int kk = 0; kk < K; kk += 16) {
    for (int i = tid; i < 64 * 16; i += 256) {
      int mm = i >> 4, kq = i & 15;
      As[kq][mm] = A[(size_t)(m0 + mm) * K + kk + kq];
    }
    for (int i = tid; i < 16 * 64; i += 256) {
      int kq = i >> 6, nn = i & 63;
      int n = n0 + nn;
      Ws[kq][nn] = (n < Ncols) ? W[(size_t)(kk + kq) * Ncols + n] : 0.f;
    }
    __syncthreads();
    #pragma unroll
    for (int kq = 0; kq < 16; ++kq) {
      float a[4], w[4];
      #pragma unroll
      for (int i = 0; i < 4; ++i) a[i] = As[kq][ty * 4 + i];
      #pragma unroll
      for (int jj = 0; jj < 4; ++jj) w[jj] = Ws[kq][tx * 4 + jj];
      #pragma unroll
      for (int i = 0; i < 4; ++i)
        #pragma unroll
        for (int jj = 0; jj < 4; ++jj) acc[i][jj] = fmaf(a[i], w[jj], acc[i][jj]);
    }
    __syncthreads();
  }
  #pragma unroll
  for (int i = 0; i < 4; ++i) {
    int m = m0 + ty * 4 + i;
    #pragma unroll
    for (int jj = 0; jj < 4; ++jj) {
      int n = n0 + tx * 4 + jj;
      if (n >= Ncols) continue;
      float v = acc[i][jj] + bias[n];
      if (ACT == 1) v = fmaxf(v, 0.f);
      else if (ACT == 2) v = 0.5f * v * (1.f + erff(v * 0.70710678118654752f));
      if (RES) v += R[(size_t)m * Ncols + n];
      Cc[(size_t)m * Ncols + n] = v;
    }
  }
}

// ---------------- bf16 MFMA GEMM: BM=32, BN=64, BK=32, 4 waves (16x32 each) ----------------
template <int ACT, int RES>
__device__ __forceinline__ void gemm_body(
    const float* __restrict__ A, const float* __restrict__ W,
    const float* __restrict__ bias, const float* __restrict__ R,
    float* __restrict__ Cc, int K, int Ncols, int m0, int n0) {
  __shared__ short As[32][40];
  __shared__ short Bs[64][40];
  int tid = threadIdx.x;
  int w = tid >> 6, l = tid & 63;
  int lq = l & 15, lg = l >> 4;
  int wr = (w & 1) * 16, wc = (w >> 1) * 32;
  int ar = tid >> 3, ak = (tid & 7) * 4;
  int wn = tid & 63, wk = (tid >> 6) * 8;
  f32x4 acc0 = {0.f, 0.f, 0.f, 0.f};
  f32x4 acc1 = {0.f, 0.f, 0.f, 0.f};
  for (int kk = 0; kk < K; kk += 32) {
    __syncthreads();
    {
      float4 a4 = *(const float4*)(A + (size_t)(m0 + ar) * K + kk + ak);
      uint2 au;
      au.x = pack2bf(a4.x, a4.y);
      au.y = pack2bf(a4.z, a4.w);
      *(uint2*)&As[ar][ak] = au;
      const float* wp = W + (size_t)(kk + wk) * Ncols + n0 + wn;
      float w0 = wp[0];
      float w1 = wp[(size_t)Ncols];
      float w2 = wp[2 * (size_t)Ncols];
      float w3 = wp[3 * (size_t)Ncols];
      float w4 = wp[4 * (size_t)Ncols];
      float w5 = wp[5 * (size_t)Ncols];
      float w6 = wp[6 * (size_t)Ncols];
      float w7 = wp[7 * (size_t)Ncols];
      uint4 wu;
      wu.x = pack2bf(w0, w1); wu.y = pack2bf(w2, w3);
      wu.z = pack2bf(w4, w5); wu.w = pack2bf(w6, w7);
      *(uint4*)&Bs[wn][wk] = wu;
    }
    __syncthreads();
    short8 af = *(short8*)&As[wr + lq][lg * 8];
    short8 b0 = *(short8*)&Bs[wc + lq][lg * 8];
    short8 b1 = *(short8*)&Bs[wc + 16 + lq][lg * 8];
    acc0 = __builtin_amdgcn_mfma_f32_16x16x32_bf16(af, b0, acc0, 0, 0, 0);
    acc1 = __builtin_amdgcn_mfma_f32_16x16x32_bf16(af, b1, acc1, 0, 0, 0);
  }
  int row = m0 + wr + lg * 4;
  #pragma unroll
  for (int r = 0; r < 4; ++r) {
    #pragma unroll
    for (int fj = 0; fj < 2; ++fj) {
      int col = n0 + wc + fj * 16 + lq;
      float v = (fj ? acc1[r] : acc0[r]) + bias[col];
      if (ACT == 1) v = fmaxf(v, 0.f);
      else if (ACT == 2) v = 0.5f * v * (1.f + erff(v * 0.70710678118654752f));
      if (RES) v += R[(size_t)(row + r) * Ncols + col];
      Cc[(size_t)(row + r) * Ncols + col] = v;
    }
  }
}

template <int ACT, int RES>
__global__ __launch_bounds__(256) void gemm_mfma(
    const float* __restrict__ A, const float* __restrict__ W,
    const float* __restrict__ bias, const float* __restrict__ R,
    float* __restrict__ Cc, int K, int Ncols) {
  gemm_body<ACT, RES>(A, W, bias, R, Cc, K, Ncols, blockIdx.y * 32, blockIdx.x * 64);
}

__global__ __launch_bounds__(256) void qkv_mfma(
    const float* __restrict__ A,
    const float* __restrict__ Wq, const float* __restrict__ Wk, const float* __restrict__ Wv,
    const float* __restrict__ bq, const float* __restrict__ bk, const float* __restrict__ bv,
    float* __restrict__ qb, float* __restrict__ kb, float* __restrict__ vb) {
  int sel = blockIdx.x >> 2;
  int n0 = (blockIdx.x & 3) << 6;
  const float* W = sel == 0 ? Wq : (sel == 1 ? Wk : Wv);
  const float* bb = sel == 0 ? bq : (sel == 1 ? bk : bv);
  float* Cc = sel == 0 ? qb : (sel == 1 ? kb : vb);
  gemm_body<0, 0>(A, W, bb, nullptr, Cc, D_, D_, blockIdx.y * 32, n0);
}

// ---------------- flash attention, bf16 MFMA ----------------
#define KSTR 40
#define VSTR 72
#define PSTR 72
__global__ __launch_bounds__(256) void attn_mfma_kernel(
    const float* __restrict__ q, const float* __restrict__ k,
    const float* __restrict__ v, float* __restrict__ o) {
  __shared__ short Ks[64][KSTR];
  __shared__ short Vt[32][VSTR];
  __shared__ short Ps[4][16][PSTR];
  int bid = blockIdx.x;
  int qt = bid & 31;
  int h  = (bid >> 5) & 7;
  int b  = bid >> 8;
  int tid = threadIdx.x;
  int w  = tid >> 6;
  int l  = tid & 63;
  int lq = l & 15;
  int lg = l >> 4;
  const size_t base = (size_t)b * ((size_t)M_ * D_) + (size_t)h * DH_;

  short8 qf;
  {
    const float* qp = q + base + (size_t)(qt * 64 + w * 16 + lq) * D_ + lg * 8;
    float4 q0 = ((const float4*)qp)[0];
    float4 q1 = ((const float4*)qp)[1];
    qf[0] = f2bf(q0.x); qf[1] = f2bf(q0.y); qf[2] = f2bf(q0.z); qf[3] = f2bf(q0.w);
    qf[4] = f2bf(q1.x); qf[5] = f2bf(q1.y); qf[6] = f2bf(q1.z); qf[7] = f2bf(q1.w);
  }
  float m_i = -INFINITY, l_i = 0.f;
  f32x4 o0 = {0.f, 0.f, 0.f, 0.f};
  f32x4 o1 = {0.f, 0.f, 0.f, 0.f};
  const float scale = 0.17677669529663687f;
  int srow = tid >> 2;
  int scol = (tid & 3) * 8;

  for (int kt = 0; kt < M_ / 64; ++kt) {
    __syncthreads();
    {
      const float* kp = k + base + (size_t)(kt * 64 + srow) * D_ + scol;
      float4 a0 = ((const float4*)kp)[0];
      float4 a1 = ((const float4*)kp)[1];
      short8 k8;
      k8[0] = f2bf(a0.x); k8[1] = f2bf(a0.y); k8[2] = f2bf(a0.z); k8[3] = f2bf(a0.w);
      k8[4] = f2bf(a1.x); k8[5] = f2bf(a1.y); k8[6] = f2bf(a1.z); k8[7] = f2bf(a1.w);
      *(short8*)&Ks[srow][scol] = k8;
      const float* vp = v + base + (size_t)(kt * 64 + srow) * D_ + scol;
      float4 b0 = ((const float4*)vp)[0];
      float4 b1 = ((const float4*)vp)[1];
      Vt[scol + 0][srow] = f2bf(b0.x);
      Vt[scol + 1][srow] = f2bf(b0.y);
      Vt[scol + 2][srow] = f2bf(b0.z);
      Vt[scol + 3][srow] = f2bf(b0.w);
      Vt[scol + 4][srow] = f2bf(b1.x);
      Vt[scol + 5][srow] = f2bf(b1.y);
      Vt[scol + 6][srow] = f2bf(b1.z);
      Vt[scol + 7][srow] = f2bf(b1.w);
    }
    __syncthreads();
    f32x4 st[4];
    #pragma unroll
    for (int t = 0; t < 4; ++t) {
      short8 kf = *(short8*)&Ks[t * 16 + lq][lg * 8];
      f32x4 z = {0.f, 0.f, 0.f, 0.f};
      st[t] = __builtin_amdgcn_mfma_f32_16x16x32_bf16(kf, qf, z, 0, 0, 0);
    }
    float smax = -INFINITY;
    #pragma unroll
    for (int t = 0; t < 4; ++t)
      #pragma unroll
      for (int r2 = 0; r2 < 4; ++r2) {
        st[t][r2] *= scale;
        smax = fmaxf(smax, st[t][r2]);
      }
    smax = fmaxf(smax, __shfl_xor(smax, 16, 64));
    smax = fmaxf(smax, __shfl_xor(smax, 32, 64));
    float m_new = fmaxf(m_i, smax);
    float fac = __expf(m_i - m_new);
    float lsum = 0.f;
    #pragma unroll
    for (int t = 0; t < 4; ++t)
      #pragma unroll
      for (int r2 = 0; r2 < 4; ++r2) {
        st[t][r2] = __expf(st[t][r2] - m_new);
        lsum += st[t][r2];
      }
    lsum += __shfl_xor(lsum, 16, 64);
    lsum += __shfl_xor(lsum, 32, 64);
    l_i = l_i * fac + lsum;
    m_i = m_new;
    #pragma unroll
    for (int r2 = 0; r2 < 4; ++r2) { o0[r2] *= fac; o1[r2] *= fac; }
    {
      unsigned* pw = (unsigned*)&Ps[w][lq][0];
      #pragma unroll
      for (int t = 0; t < 4; ++t) {
        int kv = t * 16 + lg * 4;
        pw[(kv >> 1) + 0] = pack2bf(st[t][0], st[t][1]);
        pw[(kv >> 1) + 1] = pack2bf(st[t][2], st[t][3]);
      }
    }
    #pragma unroll
    for (int c = 0; c < 2; ++c) {
      short8 pf = *(short8*)&Ps[w][lq][c * 32 + lg * 8];
      short8 v0 = *(short8*)&Vt[lq][c * 32 + lg * 8];
      short8 v1 = *(short8*)&Vt[16 + lq][c * 32 + lg * 8];
      o0 = __builtin_amdgcn_mfma_f32_16x16x32_bf16(v0, pf, o0, 0, 0, 0);
      o1 = __builtin_amdgcn_mfma_f32_16x16x32_bf16(v1, pf, o1, 0, 0, 0);
    }
  }
  float invl = 1.f / l_i;
  float* op = o + base + (size_t)(qt * 64 + w * 16 + lq) * D_;
  #pragma unroll
  for (int r2 = 0; r2 < 4; ++r2) {
    op[lg * 4 + r2]      = o0[r2] * invl;
    op[16 + lg * 4 + r2] = o1[r2] * invl;
  }
}

// ---------------- KNN top-3 + gather/mean ----------------
// 512 blocks (256 per batch), 512 threads, 64 queries/block, 8 lanes/query.
// LDS: padded float4 tile, physical index i + (i>>8)  -> chunk starts 4 banks apart.
__global__ __launch_bounds__(512) void knn_kernel(
    const float* __restrict__ xyz, const float* __restrict__ lt,
    float* __restrict__ out) {
  __shared__ float4 tok[2056];   // 2048 + 8 pad
  int b = blockIdx.x >> 8;                  // 256 blocks per batch
  int q0 = (blockIdx.x & 255) << 6;         // 64 queries per block
  int tid = threadIdx.x;
  for (int i = tid; i < M_; i += 512) {
    const float* tp = xyz + ((size_t)b * N_ + (size_t)i * 8) * 3;
    float a = tp[0], bb = tp[1], cc = tp[2];
    tok[i + (i >> 8)] = make_float4(a, bb, cc, a * a + bb * bb + cc * cc);
  }
  __syncthreads();
  int qi = tid >> 3, sl = tid & 7;
  int n = q0 + qi;
  const float* qp = xyz + ((size_t)b * N_ + n) * 3;
  float qx = qp[0], qy = qp[1], qz = qp[2];
  float q2 = qx * qx + qy * qy + qz * qz;
  float dd0 = INFINITY, dd1 = INFINITY, dd2 = INFINITY;
  int ii0 = 0, ii1 = 0, ii2 = 0;
  // per-lane chunk: ascending m order, strict < insert (ties keep lowest m)
  const float4* cp = &tok[sl * 257];
  int mb = sl << 8;
  #pragma unroll 4
  for (int j = 0; j < 256; ++j) {
    float4 t = cp[j];
    float dot = fmaf(qx, t.x, fmaf(qy, t.y, qz * t.z));
    float d = fmaxf(q2 + t.w - 2.f * dot, 0.f);
    if (d < dd2) {
      int m = mb + j;
      if (d < dd1) {
        dd2 = dd1; ii2 = ii1;
        if (d < dd0) { dd1 = dd0; ii1 = ii0; dd0 = d; ii0 = m; }
        else         { dd1 = d;  ii1 = m; }
      } else         { dd2 = d;  ii2 = m; }
    }
  }
  // merge 8 lanes (lexicographic (d, i) -> exact top_k tie semantics)
  auto insT = [&](float d, int i) {
    if (d < dd2 || (d == dd2 && i < ii2)) {
      if (d < dd1 || (d == dd1 && i < ii1)) {
        dd2 = dd1; ii2 = ii1;
        if (d < dd0 || (d == dd0 && i < ii0)) { dd1 = dd0; ii1 = ii0; dd0 = d; ii0 = i; }
        else { dd1 = d; ii1 = i; }
      } else { dd2 = d; ii2 = i; }
    }
  };
  #pragma unroll
  for (int off = 1; off < 8; off <<= 1) {
    float pd0 = __shfl_xor(dd0, off, 64); int pi0 = __shfl_xor(ii0, off, 64);
    float pd1 = __shfl_xor(dd1, off, 64); int pi1 = __shfl_xor(ii1, off, 64);
    float pd2 = __shfl_xor(dd2, off, 64); int pi2 = __shfl_xor(ii2, off, 64);
    insT(pd0, pi0); insT(pd1, pi1); insT(pd2, pi2);
  }
  const float* l0 = lt + ((size_t)b * M_ + ii0) * C_;
  const float* l1 = lt + ((size_t)b * M_ + ii1) * C_;
  const float* l2 = lt + ((size_t)b * M_ + ii2) * C_;
  float* op = out + ((size_t)b * N_ + n) * C_;
  for (int cc = sl; cc < C_; cc += 8)
    op[cc] = (l0[cc] + l1[cc] + l2[cc]) * (1.f / 3.f);
}

extern "C" void kernel_launch(void* const* d_in, const int* in_sizes, int n_in,
                              void* d_out, int out_size, void* d_ws, size_t ws_size,
                              hipStream_t stream) {
  const float* xyz  = (const float*)d_in[0];
  const float* ew1  = (const float*)d_in[1];
  const float* eb1  = (const float*)d_in[2];
  const float* ew2  = (const float*)d_in[3];
  const float* eb2  = (const float*)d_in[4];
  const float* pw1  = (const float*)d_in[5];
  const float* pb1  = (const float*)d_in[6];
  const float* pw2  = (const float*)d_in[7];
  const float* pb2  = (const float*)d_in[8];
  const float* Wq   = (const float*)d_in[9];
  const float* bq   = (const float*)d_in[10];
  const float* Wk   = (const float*)d_in[11];
  const float* bk   = (const float*)d_in[12];
  const float* Wv   = (const float*)d_in[13];
  const float* bv   = (const float*)d_in[14];
  const float* Wo   = (const float*)d_in[15];
  const float* bo   = (const float*)d_in[16];
  const float* ln1s = (const float*)d_in[17];
  const float* ln1b = (const float*)d_in[18];
  const float* W1   = (const float*)d_in[19];
  const float* b1   = (const float*)d_in[20];
  const float* W2   = (const float*)d_in[21];
  const float* b2   = (const float*)d_in[22];
  const float* ln2s = (const float*)d_in[23];
  const float* ln2b = (const float*)d_in[24];
  const float* hw1  = (const float*)d_in[25];
  const float* hb1  = (const float*)d_in[26];
  const float* hw2  = (const float*)d_in[27];
  const float* hb2  = (const float*)d_in[28];
  float* out = (float*)d_out;

  float* x  = (float*)d_ws;          // 4096*256
  float* y  = x  + (size_t)TOK_ * D_;
  float* qb = y  + (size_t)TOK_ * D_;
  float* kb = qb + (size_t)TOK_ * D_;
  float* vb = kb + (size_t)TOK_ * D_;
  float* ob = vb + (size_t)TOK_ * D_;
  float* ff = ob + (size_t)TOK_ * D_;  // 4096*512
  float* lt = ff + (size_t)TOK_ * FF_; // 4096*50

  embed_kernel<<<TOK_, 128, 0, stream>>>(xyz, ew1, eb1, ew2, eb2, pw1, pb1, pw2, pb2, x);

  dim3 gQKV(12, TOK_ / 32);  // (12, 128)
  dim3 gD(D_ / 64, TOK_ / 32);    // (4, 128)
  dim3 gF(FF_ / 64, TOK_ / 32);   // (8, 128)
  for (int l = 0; l < L_; ++l) {
    const float* wq = Wq + (size_t)l * D_ * D_;
    const float* wk = Wk + (size_t)l * D_ * D_;
    const float* wv = Wv + (size_t)l * D_ * D_;
    const float* wo = Wo + (size_t)l * D_ * D_;
    ln_kernel<<<TOK_, 64, 0, stream>>>(x, ln1s + l * D_, ln1b + l * D_, y);
    qkv_mfma<<<gQKV, 256, 0, stream>>>(y, wq, wk, wv, bq + l * D_, bk + l * D_, bv + l * D_, qb, kb, vb);
    attn_mfma_kernel<<<512, 256, 0, stream>>>(qb, kb, vb, ob);
    gemm_mfma<0, 1><<<gD, 256, 0, stream>>>(ob, wo, bo + l * D_, x, x, D_, D_);
    ln_kernel<<<TOK_, 64, 0, stream>>>(x, ln2s + l * D_, ln2b + l * D_, y);
    gemm_mfma<2, 0><<<gF, 256, 0, stream>>>(y, W1 + (size_t)l * D_ * FF_, b1 + l * FF_, nullptr, ff, D_, FF_);
    gemm_mfma<0, 1><<<gD, 256, 0, stream>>>(ff, W2 + (size_t)l * FF_ * D_, b2 + l * D_, x, x, FF_, D_);
  }
  gemm_mfma<1, 0><<<dim3(HHID_ / 64, TOK_ / 32), 256, 0, stream>>>(x, hw1, hb1, nullptr, y, D_, HHID_);
  gemm_kernel<0, 0><<<dim3(1, TOK_ / 64), 256, 0, stream>>>(y, hw2, hb2, nullptr, lt, HHID_, C_);
  knn_kernel<<<512, 512, 0, stream>>>(xyz, lt, out);
}

// Round 5
// 497.619 us; speedup vs baseline: 5.5290x; 1.0768x over previous
//
#include <hip/hip_runtime.h>
#include <hip/hip_bf16.h>
#include <math.h>

#define B_ 2
#define N_ 16384
#define M_ 2048
#define D_ 256
#define NHEAD_ 8
#define DH_ 32
#define FF_ 512
#define C_ 50
#define HID_ 128
#define HHID_ 256
#define L_ 4
#define EPS_ 1e-5f
#define TOK_ (B_*M_)   // 4096
// (1/sqrt(32)) * log2(e): folds softmax scale AND exp->exp2 into Q
#define QSCALE_ 0.25507604155757994f

typedef short short8 __attribute__((ext_vector_type(8)));
typedef float f32x4 __attribute__((ext_vector_type(4)));

__device__ __forceinline__ short f2bf(float f) {
  union { float f; unsigned u; } c; c.f = f;
  unsigned u = c.u;
  unsigned r = (u + 0x7FFFu + ((u >> 16) & 1u)) >> 16;
  return (short)r;
}
__device__ __forceinline__ unsigned pack2bf(float a, float b) {
  return ((unsigned)(unsigned short)f2bf(a)) | (((unsigned)(unsigned short)f2bf(b)) << 16);
}
__device__ __forceinline__ float fast_exp2(float x) {
  float r;
  asm("v_exp_f32 %0, %1" : "=v"(r) : "v"(x));
  return r;
}
__device__ __forceinline__ unsigned cvt_pk_bf16(float lo, float hi) {
  unsigned r;
  asm("v_cvt_pk_bf16_f32 %0, %1, %2" : "=v"(r) : "v"(lo), "v"(hi));
  return r;
}

// ---------------- fused embed + pos MLP ----------------
__global__ __launch_bounds__(128) void embed_kernel(
    const float* __restrict__ xyz,
    const float* __restrict__ ew1, const float* __restrict__ eb1,
    const float* __restrict__ ew2, const float* __restrict__ eb2,
    const float* __restrict__ pw1, const float* __restrict__ pb1,
    const float* __restrict__ pw2, const float* __restrict__ pb2,
    float* __restrict__ x) {
  int t = blockIdx.x;           // 0..4095
  int b = t / M_, m = t % M_;
  const float* p = xyz + ((size_t)b * N_ + (size_t)m * 8) * 3;
  float t0 = p[0], t1 = p[1], t2 = p[2];
  __shared__ float he[HID_], hp[HID_];
  int j = threadIdx.x;          // 128 threads
  {
    float a = fmaf(t0, ew1[j], fmaf(t1, ew1[HID_ + j], fmaf(t2, ew1[2 * HID_ + j], eb1[j])));
    he[j] = fmaxf(a, 0.f);
    float c = fmaf(t0, pw1[j], fmaf(t1, pw1[HID_ + j], fmaf(t2, pw1[2 * HID_ + j], pb1[j])));
    hp[j] = fmaxf(c, 0.f);
  }
  __syncthreads();
  for (int d = j; d < D_; d += HID_) {
    float acc = eb2[d] + pb2[d];
    for (int k = 0; k < HID_; ++k) {
      acc = fmaf(he[k], ew2[k * D_ + d], acc);
      acc = fmaf(hp[k], pw2[k * D_ + d], acc);
    }
    x[(size_t)t * D_ + d] = acc;
  }
}

// ---------------- LayerNorm (one wave per row) ----------------
__global__ __launch_bounds__(64) void ln_kernel(
    const float* __restrict__ x, const float* __restrict__ s,
    const float* __restrict__ bb, float* __restrict__ y) {
  int r = blockIdx.x;
  int t = threadIdx.x;  // 64
  const float4* xr = (const float4*)(x + (size_t)r * D_);
  float4 v = xr[t];
  float sum = v.x + v.y + v.z + v.w;
  #pragma unroll
  for (int o = 1; o < 64; o <<= 1) sum += __shfl_xor(sum, o, 64);
  float mean = sum * (1.f / D_);
  float dx = v.x - mean, dy = v.y - mean, dz = v.z - mean, dw = v.w - mean;
  float vs = dx * dx + dy * dy + dz * dz + dw * dw;
  #pragma unroll
  for (int o = 1; o < 64; o <<= 1) vs += __shfl_xor(vs, o, 64);
  float inv = 1.0f / sqrtf(vs * (1.f / D_) + EPS_);
  float4 sv = ((const float4*)s)[t];
  float4 bv = ((const float4*)bb)[t];
  float4 out;
  out.x = dx * inv * sv.x + bv.x;
  out.y = dy * inv * sv.y + bv.y;
  out.z = dz * inv * sv.z + bv.z;
  out.w = dw * inv * sv.w + bv.w;
  ((float4*)(y + (size_t)r * D_))[t] = out;
}

// ---------------- fp32 tiled GEMM (kept for head2, N=50) ----------------
template <int ACT, int RES>
__global__ __launch_bounds__(256) void gemm_kernel(
    const float* __restrict__ A, const float* __restrict__ W,
    const float* __restrict__ bias, const float* __restrict__ R,
    float* __restrict__ Cc, int K, int Ncols) {
  __shared__ float As[16][68];
  __shared__ float Ws[16][68];
  int m0 = blockIdx.y * 64;
  int n0 = blockIdx.x * 64;
  int tid = threadIdx.x;  // 256
  int tx = tid & 15, ty = tid >> 4;
  float acc[4][4] = {};
  for (int kk = 0; kk < K; kk += 16) {
    for (int i = tid; i < 64 * 16; i += 256) {
      int mm = i >> 4, kq = i & 15;
      As[kq][mm] = A[(size_t)(m0 + mm) * K + kk + kq];
    }
    for (int i = tid; i < 16 * 64; i += 256) {
      int kq = i >> 6, nn = i & 63;
      int n = n0 + nn;
      Ws[kq][nn] = (n < Ncols) ? W[(size_t)(kk + kq) * Ncols + n] : 0.f;
    }
    __syncthreads();
    #pragma unroll
    for (int kq = 0; kq < 16; ++kq) {
      float a[4], w[4];
      #pragma unroll
      for (int i = 0; i < 4; ++i) a[i] = As[kq][ty * 4 + i];
      #pragma unroll
      for (int jj = 0; jj < 4; ++jj) w[jj] = Ws[kq][tx * 4 + jj];
      #pragma unroll
      for (int i = 0; i < 4; ++i)
        #pragma unroll
        for (int jj = 0; jj < 4; ++jj) acc[i][jj] = fmaf(a[i], w[jj], acc[i][jj]);
    }
    __syncthreads();
  }
  #pragma unroll
  for (int i = 0; i < 4; ++i) {
    int m = m0 + ty * 4 + i;
    #pragma unroll
    for (int jj = 0; jj < 4; ++jj) {
      int n = n0 + tx * 4 + jj;
      if (n >= Ncols) continue;
      float v = acc[i][jj] + bias[n];
      if (ACT == 1) v = fmaxf(v, 0.f);
      else if (ACT == 2) v = 0.5f * v * (1.f + erff(v * 0.70710678118654752f));
      if (RES) v += R[(size_t)m * Ncols + n];
      Cc[(size_t)m * Ncols + n] = v;
    }
  }
}

// ---------------- bf16 MFMA GEMM: BM=32, BN=64, BK=32, 4 waves (16x32 each) ----------------
// out16 != nullptr -> write bf16 (value * oscale) instead of fp32.
template <int ACT, int RES>
__device__ __forceinline__ void gemm_body(
    const float* __restrict__ A, const float* __restrict__ W,
    const float* __restrict__ bias, const float* __restrict__ R,
    float* __restrict__ Cc, short* __restrict__ out16, float oscale,
    int K, int Ncols, int m0, int n0) {
  __shared__ short As[32][40];
  __shared__ short Bs[64][40];
  int tid = threadIdx.x;
  int w = tid >> 6, l = tid & 63;
  int lq = l & 15, lg = l >> 4;
  int wr = (w & 1) * 16, wc = (w >> 1) * 32;
  int ar = tid >> 3, ak = (tid & 7) * 4;
  int wn = tid & 63, wk = (tid >> 6) * 8;
  f32x4 acc0 = {0.f, 0.f, 0.f, 0.f};
  f32x4 acc1 = {0.f, 0.f, 0.f, 0.f};
  for (int kk = 0; kk < K; kk += 32) {
    __syncthreads();
    {
      float4 a4 = *(const float4*)(A + (size_t)(m0 + ar) * K + kk + ak);
      uint2 au;
      au.x = pack2bf(a4.x, a4.y);
      au.y = pack2bf(a4.z, a4.w);
      *(uint2*)&As[ar][ak] = au;
      const float* wp = W + (size_t)(kk + wk) * Ncols + n0 + wn;
      float w0 = wp[0];
      float w1 = wp[(size_t)Ncols];
      float w2 = wp[2 * (size_t)Ncols];
      float w3 = wp[3 * (size_t)Ncols];
      float w4 = wp[4 * (size_t)Ncols];
      float w5 = wp[5 * (size_t)Ncols];
      float w6 = wp[6 * (size_t)Ncols];
      float w7 = wp[7 * (size_t)Ncols];
      uint4 wu;
      wu.x = pack2bf(w0, w1); wu.y = pack2bf(w2, w3);
      wu.z = pack2bf(w4, w5); wu.w = pack2bf(w6, w7);
      *(uint4*)&Bs[wn][wk] = wu;
    }
    __syncthreads();
    short8 af = *(short8*)&As[wr + lq][lg * 8];
    short8 b0 = *(short8*)&Bs[wc + lq][lg * 8];
    short8 b1 = *(short8*)&Bs[wc + 16 + lq][lg * 8];
    acc0 = __builtin_amdgcn_mfma_f32_16x16x32_bf16(af, b0, acc0, 0, 0, 0);
    acc1 = __builtin_amdgcn_mfma_f32_16x16x32_bf16(af, b1, acc1, 0, 0, 0);
  }
  int row = m0 + wr + lg * 4;
  #pragma unroll
  for (int r = 0; r < 4; ++r) {
    #pragma unroll
    for (int fj = 0; fj < 2; ++fj) {
      int col = n0 + wc + fj * 16 + lq;
      float v = (fj ? acc1[r] : acc0[r]) + bias[col];
      if (ACT == 1) v = fmaxf(v, 0.f);
      else if (ACT == 2) v = 0.5f * v * (1.f + erff(v * 0.70710678118654752f));
      if (RES) v += R[(size_t)(row + r) * Ncols + col];
      if (out16) out16[(size_t)(row + r) * Ncols + col] = f2bf(v * oscale);
      else Cc[(size_t)(row + r) * Ncols + col] = v;
    }
  }
}

template <int ACT, int RES>
__global__ __launch_bounds__(256) void gemm_mfma(
    const float* __restrict__ A, const float* __restrict__ W,
    const float* __restrict__ bias, const float* __restrict__ R,
    float* __restrict__ Cc, int K, int Ncols) {
  gemm_body<ACT, RES>(A, W, bias, R, Cc, nullptr, 1.f, K, Ncols, blockIdx.y * 32, blockIdx.x * 64);
}

// Q -> bf16 (scaled by QSCALE_), K -> bf16, V -> fp32
__global__ __launch_bounds__(256) void qkv_mfma(
    const float* __restrict__ A,
    const float* __restrict__ Wq, const float* __restrict__ Wk, const float* __restrict__ Wv,
    const float* __restrict__ bq, const float* __restrict__ bk, const float* __restrict__ bv,
    short* __restrict__ q16, short* __restrict__ k16, float* __restrict__ vb) {
  int sel = blockIdx.x >> 2;
  int n0 = (blockIdx.x & 3) << 6;
  const float* W = sel == 0 ? Wq : (sel == 1 ? Wk : Wv);
  const float* bb = sel == 0 ? bq : (sel == 1 ? bk : bv);
  short* out16 = sel == 0 ? q16 : (sel == 1 ? k16 : nullptr);
  float oscale = sel == 0 ? QSCALE_ : 1.f;
  gemm_body<0, 0>(A, W, bb, nullptr, vb, out16, oscale, D_, D_, blockIdx.y * 32, n0);
}

// ---------------- V transpose: vb fp32 [tok][256] -> vt16 bf16 [b][h][32][2048] ----------------
__global__ __launch_bounds__(256) void vtrans_kernel(
    const float* __restrict__ vb, short* __restrict__ vt16) {
  int bid = blockIdx.x;
  int mt = bid & 31;
  int h = (bid >> 5) & 7;
  int b = bid >> 8;
  __shared__ short ts[64][34];
  int m0 = mt * 64;
  int tid = threadIdx.x;
  int mm = tid >> 2, dd = (tid & 3) * 8;
  const float* vp = vb + (size_t)(b * M_ + m0 + mm) * D_ + h * DH_ + dd;
  float4 a0 = ((const float4*)vp)[0];
  float4 a1 = ((const float4*)vp)[1];
  ts[mm][dd + 0] = f2bf(a0.x); ts[mm][dd + 1] = f2bf(a0.y);
  ts[mm][dd + 2] = f2bf(a0.z); ts[mm][dd + 3] = f2bf(a0.w);
  ts[mm][dd + 4] = f2bf(a1.x); ts[mm][dd + 5] = f2bf(a1.y);
  ts[mm][dd + 6] = f2bf(a1.z); ts[mm][dd + 7] = f2bf(a1.w);
  __syncthreads();
  int d = tid >> 3, mc = (tid & 7) * 8;
  short8 r;
  #pragma unroll
  for (int j = 0; j < 8; ++j) r[j] = ts[mc + j][d];
  *(short8*)&vt16[(size_t)((b * NHEAD_ + h) * DH_ + d) * M_ + m0 + mc] = r;
}

// ---------------- flash attention, bf16 MFMA, pre-converted inputs ----------------
#define KSTR 40
#define VSTR 72
#define PSTR 72
__global__ __launch_bounds__(256) void attn_mfma_kernel(
    const short* __restrict__ q16, const short* __restrict__ k16,
    const short* __restrict__ vt16, float* __restrict__ o) {
  __shared__ short Ks[64][KSTR];
  __shared__ short Vt[32][VSTR];
  __shared__ short Ps[4][16][PSTR];
  int bid = blockIdx.x;
  int qt = bid & 31;
  int h  = (bid >> 5) & 7;
  int b  = bid >> 8;
  int tid = threadIdx.x;
  int w  = tid >> 6;
  int l  = tid & 63;
  int lq = l & 15;
  int lg = l >> 4;

  // Q frag: bf16, pre-scaled (log2-domain)
  short8 qf = *(const short8*)&q16[(size_t)(b * M_ + qt * 64 + w * 16 + lq) * D_ + h * DH_ + lg * 8];

  float m_i = -INFINITY, l_i = 0.f;
  f32x4 o0 = {0.f, 0.f, 0.f, 0.f};
  f32x4 o1 = {0.f, 0.f, 0.f, 0.f};
  int srow = tid >> 2, scol = (tid & 3) * 8;     // K staging
  int vd = tid >> 3, vm = (tid & 7) * 8;         // V^T staging
  const short* kp = k16 + (size_t)(b * M_) * D_ + h * DH_ + (size_t)srow * D_ + scol;
  const short* vp = vt16 + (size_t)((b * NHEAD_ + h) * DH_ + vd) * M_ + vm;

  for (int kt = 0; kt < M_ / 64; ++kt) {
    __syncthreads();
    *(short8*)&Ks[srow][scol] = *(const short8*)(kp + (size_t)(kt * 64) * D_);
    *(short8*)&Vt[vd][vm]     = *(const short8*)(vp + kt * 64);
    __syncthreads();
    // S'^T[kv][q] = K-tile · Q^T (log2-domain)
    f32x4 st[4];
    #pragma unroll
    for (int t = 0; t < 4; ++t) {
      short8 kf = *(short8*)&Ks[t * 16 + lq][lg * 8];
      f32x4 z = {0.f, 0.f, 0.f, 0.f};
      st[t] = __builtin_amdgcn_mfma_f32_16x16x32_bf16(kf, qf, z, 0, 0, 0);
    }
    float smax = -INFINITY;
    #pragma unroll
    for (int t = 0; t < 4; ++t)
      #pragma unroll
      for (int r2 = 0; r2 < 4; ++r2) smax = fmaxf(smax, st[t][r2]);
    smax = fmaxf(smax, __shfl_xor(smax, 16, 64));
    smax = fmaxf(smax, __shfl_xor(smax, 32, 64));
    float m_new = fmaxf(m_i, smax);
    float fac = fast_exp2(m_i - m_new);
    float lsum = 0.f;
    #pragma unroll
    for (int t = 0; t < 4; ++t)
      #pragma unroll
      for (int r2 = 0; r2 < 4; ++r2) {
        st[t][r2] = fast_exp2(st[t][r2] - m_new);
        lsum += st[t][r2];
      }
    lsum += __shfl_xor(lsum, 16, 64);
    lsum += __shfl_xor(lsum, 32, 64);
    l_i = l_i * fac + lsum;
    m_i = m_new;
    #pragma unroll
    for (int r2 = 0; r2 < 4; ++r2) { o0[r2] *= fac; o1[r2] *= fac; }
    // pack P (bf16) into per-wave LDS: Ps[w][q][kv]
    {
      unsigned* pw = (unsigned*)&Ps[w][lq][0];
      #pragma unroll
      for (int t = 0; t < 4; ++t) {
        uint2 pk;
        pk.x = cvt_pk_bf16(st[t][0], st[t][1]);
        pk.y = cvt_pk_bf16(st[t][2], st[t][3]);
        *(uint2*)(pw + t * 8 + lg * 2) = pk;
      }
    }
    // O^T += V^T · P
    #pragma unroll
    for (int c = 0; c < 2; ++c) {
      short8 pf = *(short8*)&Ps[w][lq][c * 32 + lg * 8];
      short8 v0 = *(short8*)&Vt[lq][c * 32 + lg * 8];
      short8 v1 = *(short8*)&Vt[16 + lq][c * 32 + lg * 8];
      o0 = __builtin_amdgcn_mfma_f32_16x16x32_bf16(v0, pf, o0, 0, 0, 0);
      o1 = __builtin_amdgcn_mfma_f32_16x16x32_bf16(v1, pf, o1, 0, 0, 0);
    }
  }
  float invl = 1.f / l_i;
  float* op = o + (size_t)(b * M_ + qt * 64 + w * 16 + lq) * D_ + h * DH_;
  #pragma unroll
  for (int r2 = 0; r2 < 4; ++r2) {
    op[lg * 4 + r2]      = o0[r2] * invl;
    op[16 + lg * 4 + r2] = o1[r2] * invl;
  }
}

// ---------------- KNN top-3 + gather/mean ----------------
__global__ __launch_bounds__(512) void knn_kernel(
    const float* __restrict__ xyz, const float* __restrict__ lt,
    float* __restrict__ out) {
  __shared__ float4 tok[2056];   // 2048 + 8 pad
  int b = blockIdx.x >> 8;                  // 256 blocks per batch
  int q0 = (blockIdx.x & 255) << 6;         // 64 queries per block
  int tid = threadIdx.x;
  for (int i = tid; i < M_; i += 512) {
    const float* tp = xyz + ((size_t)b * N_ + (size_t)i * 8) * 3;
    float a = tp[0], bb = tp[1], cc = tp[2];
    tok[i + (i >> 8)] = make_float4(a, bb, cc, a * a + bb * bb + cc * cc);
  }
  __syncthreads();
  int qi = tid >> 3, sl = tid & 7;
  int n = q0 + qi;
  const float* qp = xyz + ((size_t)b * N_ + n) * 3;
  float qx = qp[0], qy = qp[1], qz = qp[2];
  float q2 = qx * qx + qy * qy + qz * qz;
  float dd0 = INFINITY, dd1 = INFINITY, dd2 = INFINITY;
  int ii0 = 0, ii1 = 0, ii2 = 0;
  const float4* cp = &tok[sl * 257];
  int mb = sl << 8;
  #pragma unroll 4
  for (int j = 0; j < 256; ++j) {
    float4 t = cp[j];
    float dot = fmaf(qx, t.x, fmaf(qy, t.y, qz * t.z));
    float d = fmaxf(q2 + t.w - 2.f * dot, 0.f);
    if (d < dd2) {
      int m = mb + j;
      if (d < dd1) {
        dd2 = dd1; ii2 = ii1;
        if (d < dd0) { dd1 = dd0; ii1 = ii0; dd0 = d; ii0 = m; }
        else         { dd1 = d;  ii1 = m; }
      } else         { dd2 = d;  ii2 = m; }
    }
  }
  auto insT = [&](float d, int i) {
    if (d < dd2 || (d == dd2 && i < ii2)) {
      if (d < dd1 || (d == dd1 && i < ii1)) {
        dd2 = dd1; ii2 = ii1;
        if (d < dd0 || (d == dd0 && i < ii0)) { dd1 = dd0; ii1 = ii0; dd0 = d; ii0 = i; }
        else { dd1 = d; ii1 = i; }
      } else { dd2 = d; ii2 = i; }
    }
  };
  #pragma unroll
  for (int off = 1; off < 8; off <<= 1) {
    float pd0 = __shfl_xor(dd0, off, 64); int pi0 = __shfl_xor(ii0, off, 64);
    float pd1 = __shfl_xor(dd1, off, 64); int pi1 = __shfl_xor(ii1, off, 64);
    float pd2 = __shfl_xor(dd2, off, 64); int pi2 = __shfl_xor(ii2, off, 64);
    insT(pd0, pi0); insT(pd1, pi1); insT(pd2, pi2);
  }
  const float* l0 = lt + ((size_t)b * M_ + ii0) * C_;
  const float* l1 = lt + ((size_t)b * M_ + ii1) * C_;
  const float* l2 = lt + ((size_t)b * M_ + ii2) * C_;
  float* op = out + ((size_t)b * N_ + n) * C_;
  for (int cc = sl; cc < C_; cc += 8)
    op[cc] = (l0[cc] + l1[cc] + l2[cc]) * (1.f / 3.f);
}

extern "C" void kernel_launch(void* const* d_in, const int* in_sizes, int n_in,
                              void* d_out, int out_size, void* d_ws, size_t ws_size,
                              hipStream_t stream) {
  const float* xyz  = (const float*)d_in[0];
  const float* ew1  = (const float*)d_in[1];
  const float* eb1  = (const float*)d_in[2];
  const float* ew2  = (const float*)d_in[3];
  const float* eb2  = (const float*)d_in[4];
  const float* pw1  = (const float*)d_in[5];
  const float* pb1  = (const float*)d_in[6];
  const float* pw2  = (const float*)d_in[7];
  const float* pb2  = (const float*)d_in[8];
  const float* Wq   = (const float*)d_in[9];
  const float* bq   = (const float*)d_in[10];
  const float* Wk   = (const float*)d_in[11];
  const float* bk   = (const float*)d_in[12];
  const float* Wv   = (const float*)d_in[13];
  const float* bv   = (const float*)d_in[14];
  const float* Wo   = (const float*)d_in[15];
  const float* bo   = (const float*)d_in[16];
  const float* ln1s = (const float*)d_in[17];
  const float* ln1b = (const float*)d_in[18];
  const float* W1   = (const float*)d_in[19];
  const float* b1   = (const float*)d_in[20];
  const float* W2   = (const float*)d_in[21];
  const float* b2   = (const float*)d_in[22];
  const float* ln2s = (const float*)d_in[23];
  const float* ln2b = (const float*)d_in[24];
  const float* hw1  = (const float*)d_in[25];
  const float* hb1  = (const float*)d_in[26];
  const float* hw2  = (const float*)d_in[27];
  const float* hb2  = (const float*)d_in[28];
  float* out = (float*)d_out;

  float* x  = (float*)d_ws;            // 4096*256 f32
  float* y  = x  + (size_t)TOK_ * D_;
  float* qb = y  + (size_t)TOK_ * D_;  // region reused: qb16 + kb16 (bf16)
  float* kb = qb + (size_t)TOK_ * D_;  // region reused: vt16 (bf16)
  float* vb = kb + (size_t)TOK_ * D_;  // V fp32
  float* ob = vb + (size_t)TOK_ * D_;
  float* ff = ob + (size_t)TOK_ * D_;  // 4096*512
  float* lt = ff + (size_t)TOK_ * FF_; // 4096*50

  short* qb16 = (short*)qb;
  short* kb16 = qb16 + (size_t)TOK_ * D_;
  short* vt16 = (short*)kb;

  embed_kernel<<<TOK_, 128, 0, stream>>>(xyz, ew1, eb1, ew2, eb2, pw1, pb1, pw2, pb2, x);

  dim3 gQKV(12, TOK_ / 32);       // (12, 128)
  dim3 gD(D_ / 64, TOK_ / 32);    // (4, 128)
  dim3 gF(FF_ / 64, TOK_ / 32);   // (8, 128)
  for (int l = 0; l < L_; ++l) {
    const float* wq = Wq + (size_t)l * D_ * D_;
    const float* wk = Wk + (size_t)l * D_ * D_;
    const float* wv = Wv + (size_t)l * D_ * D_;
    const float* wo = Wo + (size_t)l * D_ * D_;
    ln_kernel<<<TOK_, 64, 0, stream>>>(x, ln1s + l * D_, ln1b + l * D_, y);
    qkv_mfma<<<gQKV, 256, 0, stream>>>(y, wq, wk, wv, bq + l * D_, bk + l * D_, bv + l * D_, qb16, kb16, vb);
    vtrans_kernel<<<512, 256, 0, stream>>>(vb, vt16);
    attn_mfma_kernel<<<512, 256, 0, stream>>>(qb16, kb16, vt16, ob);
    gemm_mfma<0, 1><<<gD, 256, 0, stream>>>(ob, wo, bo + l * D_, x, x, D_, D_);
    ln_kernel<<<TOK_, 64, 0, stream>>>(x, ln2s + l * D_, ln2b + l * D_, y);
    gemm_mfma<2, 0><<<gF, 256, 0, stream>>>(y, W1 + (size_t)l * D_ * FF_, b1 + l * FF_, nullptr, ff, D_, FF_);
    gemm_mfma<0, 1><<<gD, 256, 0, stream>>>(ff, W2 + (size_t)l * FF_ * D_, b2 + l * D_, x, x, FF_, D_);
  }
  gemm_mfma<1, 0><<<dim3(HHID_ / 64, TOK_ / 32), 256, 0, stream>>>(x, hw1, hb1, nullptr, y, D_, HHID_);
  gemm_kernel<0, 0><<<dim3(1, TOK_ / 64), 256, 0, stream>>>(y, hw2, hb2, nullptr, lt, HHID_, C_);
  knn_kernel<<<512, 512, 0, stream>>>(xyz, lt, out);
}